// Round 3
// baseline (1477.285 us; speedup 1.0000x reference)
//
#include <hip/hip_runtime.h>
#include <hip/hip_bf16.h>
#include <cstddef>

// ---------------------------------------------------------------------------
// Problem dims (compile-time constants from the reference)
// ---------------------------------------------------------------------------
#define VOCAB 50000
#define EDIM  200
#define HDIM  128
#define BB 16
#define RR 10
#define SS 20
#define WW 64
#define NSENT (BB*RR*SS)   // 3200 word-level sequences
#define NREV  (BB*RR)      // 160 sentence-level sequences
#define G3    (3*HDIM)     // 384 gate rows per direction
#define NPROJ (2*G3)       // 768 (fwd+bwd concatenated)

// ---------------------------------------------------------------------------
// Generic tiled f32 GEMM:  C[M x 768] = A[M x K] @ [B0;B1]^T + [bias0;bias1]
// ---------------------------------------------------------------------------
#define TS 64
#define KC 32

__global__ __launch_bounds__(256) void gemm2_bias(
    const float* __restrict__ A0, const float* __restrict__ A1,
    int M, int K,
    const float* __restrict__ B0, const float* __restrict__ B1,
    const float* __restrict__ bias0, const float* __restrict__ bias1,
    float* __restrict__ C)
{
    __shared__ __align__(16) float At[KC][TS + 4];
    __shared__ __align__(16) float Bt[KC][TS + 4];

    const int ct = blockIdx.x;            // col tiles over 768
    const int rt = blockIdx.y;            // row tiles over M
    const int tid = threadIdx.x;
    const int r0 = (tid >> 4) << 2;
    const int c0 = (tid & 15) << 2;
    const int rowBase = rt * TS;
    const int colBase = ct * TS;

    const float* Bsrc = (colBase < G3) ? B0 : B1;
    const int bcolBase = (colBase < G3) ? colBase : (colBase - G3);

    float acc[4][4];
    #pragma unroll
    for (int i = 0; i < 4; ++i)
        #pragma unroll
        for (int j = 0; j < 4; ++j) acc[i][j] = 0.f;

    for (int k0 = 0; k0 < K; k0 += KC) {
        const int kc = min(KC, K - k0);
        for (int f = tid; f < TS * KC; f += 256) {
            int r = f >> 5;
            int k = f & 31;
            float v = 0.f;
            int row = rowBase + r;
            if (k < kc && row < M) {
                size_t idx = (size_t)row * K + k0 + k;
                v = A0[idx];
                if (A1) v = 0.5f * (v + A1[idx]);
            }
            At[k][r] = v;
        }
        for (int f = tid; f < TS * KC; f += 256) {
            int r = f >> 5;
            int k = f & 31;
            float v = 0.f;
            if (k < kc) v = Bsrc[(size_t)(bcolBase + r) * K + k0 + k];
            Bt[k][r] = v;
        }
        __syncthreads();
        #pragma unroll 8
        for (int k = 0; k < kc; ++k) {
            float4 av = *(const float4*)&At[k][r0];
            float4 bv = *(const float4*)&Bt[k][c0];
            acc[0][0] = fmaf(av.x, bv.x, acc[0][0]);
            acc[0][1] = fmaf(av.x, bv.y, acc[0][1]);
            acc[0][2] = fmaf(av.x, bv.z, acc[0][2]);
            acc[0][3] = fmaf(av.x, bv.w, acc[0][3]);
            acc[1][0] = fmaf(av.y, bv.x, acc[1][0]);
            acc[1][1] = fmaf(av.y, bv.y, acc[1][1]);
            acc[1][2] = fmaf(av.y, bv.z, acc[1][2]);
            acc[1][3] = fmaf(av.y, bv.w, acc[1][3]);
            acc[2][0] = fmaf(av.z, bv.x, acc[2][0]);
            acc[2][1] = fmaf(av.z, bv.y, acc[2][1]);
            acc[2][2] = fmaf(av.z, bv.z, acc[2][2]);
            acc[2][3] = fmaf(av.z, bv.w, acc[2][3]);
            acc[3][0] = fmaf(av.w, bv.x, acc[3][0]);
            acc[3][1] = fmaf(av.w, bv.y, acc[3][1]);
            acc[3][2] = fmaf(av.w, bv.z, acc[3][2]);
            acc[3][3] = fmaf(av.w, bv.w, acc[3][3]);
        }
        __syncthreads();
    }

    const float* bsrc = (colBase < G3) ? bias0 : bias1;
    #pragma unroll
    for (int i = 0; i < 4; ++i) {
        int row = rowBase + r0 + i;
        if (row < M) {
            float* cp = C + (size_t)row * NPROJ + colBase + c0;
            #pragma unroll
            for (int j = 0; j < 4; ++j)
                cp[j] = acc[i][j] + bsrc[bcolBase + c0 + j];
        }
    }
}

// ---------------------------------------------------------------------------
// GRU scan: ONE (sequence, direction) per block.
// Block: 384 threads = 6 waves. Thread tid owns gate row tid, with
// Whh[tid,:] persisted in 128 regs. h (128 f32) lives in LDS and is read by
// wave-uniform broadcast float4 loads (32 instr/wave/step, 16B each).
// Each block runs exactly its own len steps (no tile imbalance); 5 blocks/CU
// (wave cap) give independent barrier domains that hide each other's
// gather/barrier latency. xg gather for step t+1 is issued before step t's
// matvec so L3 latency hides under the FMAs.
// ---------------------------------------------------------------------------
template<bool WORD, int TMAX>
__global__ __launch_bounds__(384) void gru_seq(
    const float* __restrict__ table,    // [*, 768] projected-input table
    const int*   __restrict__ tokens,   // word-level: [numSeq*WW]; else unused
    const int*   __restrict__ lengths,  // [numSeq]
    const float* __restrict__ Whh_f, const float* __restrict__ Whh_b,
    const float* __restrict__ bhh_f, const float* __restrict__ bhh_b,
    float* __restrict__ hout_f, float* __restrict__ hout_b,
    int numSeq)
{
    const int bid = blockIdx.x;
    const int dir = (bid >= numSeq) ? 1 : 0;
    const int seq = dir ? (bid - numSeq) : bid;
    const int tid = threadIdx.x;        // gate row 0..383

    const float* Whh = dir ? Whh_b : Whh_f;
    float w[128];
    #pragma unroll
    for (int i = 0; i < 32; ++i) {
        float4 v = *(const float4*)(Whh + (size_t)tid * HDIM + 4 * i);
        w[4*i+0] = v.x; w[4*i+1] = v.y; w[4*i+2] = v.z; w[4*i+3] = v.w;
    }
    const float bhh_r = (dir ? bhh_b : bhh_f)[tid];

    __shared__ __align__(16) float sh_h[HDIM];
    __shared__ float sh_hg[G3];
    __shared__ int sh_tok[WORD ? WW : 1];

    const int len = lengths[seq];
    if (WORD) {
        if (tid < WW) sh_tok[tid] = tokens[(size_t)seq * WW + tid];
    }
    if (tid < HDIM) sh_h[tid] = 0.f;
    __syncthreads();

    const int e = tid;                  // gate element for tid < 128
    float pr = 0.f, pz = 0.f, pn = 0.f; // current step's xg (prefetched)
    if (tid < HDIM && len > 0) {
        int tt = dir ? (len - 1) : 0;
        size_t row = WORD ? (size_t)sh_tok[tt] : ((size_t)seq * TMAX + tt);
        const float* xg = table + row * NPROJ + dir * G3 + e;
        pr = xg[0]; pz = xg[HDIM]; pn = xg[2*HDIM];
    }

    for (int t = 0; t < len; ++t) {
        // issue next step's gather now; latency hides under the matvec
        float qr = 0.f, qz = 0.f, qn = 0.f;
        if (tid < HDIM && t + 1 < len) {
            int tt = dir ? (len - 2 - t) : (t + 1);
            size_t row = WORD ? (size_t)sh_tok[tt] : ((size_t)seq * TMAX + tt);
            const float* xg = table + row * NPROJ + dir * G3 + e;
            qr = xg[0]; qz = xg[HDIM]; qn = xg[2*HDIM];
        }
        // hg = Whh @ h + bhh  (broadcast LDS reads, weights in regs)
        const float4* h4 = (const float4*)sh_h;
        float a0 = 0.f, a1 = 0.f, a2 = 0.f, a3 = 0.f;
        #pragma unroll
        for (int i = 0; i < 32; ++i) {
            float4 hv = h4[i];
            a0 = fmaf(w[4*i+0], hv.x, a0);
            a1 = fmaf(w[4*i+1], hv.y, a1);
            a2 = fmaf(w[4*i+2], hv.z, a2);
            a3 = fmaf(w[4*i+3], hv.w, a3);
        }
        float hg = ((a0 + a1) + (a2 + a3)) + bhh_r;
        sh_hg[tid] = hg;
        __syncthreads();
        // gate update on threads 0..127 (own hg is the r-gate row)
        if (tid < HDIM) {
            float hgz = sh_hg[e + HDIM];
            float hgn = sh_hg[e + 2*HDIM];
            float hold = sh_h[e];
            float r = 1.f / (1.f + expf(-(pr + hg)));
            float z = 1.f / (1.f + expf(-(pz + hgz)));
            float n = tanhf(pn + r * hgn);
            sh_h[e] = (1.f - z) * n + z * hold;
        }
        __syncthreads();
        pr = qr; pz = qz; pn = qn;
    }

    if (tid < HDIM) {
        float* hout = dir ? hout_b : hout_f;
        hout[(size_t)seq * HDIM + tid] = sh_h[tid];
    }
}

// ---------------------------------------------------------------------------
// Head: rev = 0.5*(hsf+hsb); h1 = selu(rev @ fc1^T + b1); r = h1 @ fc2^T + b2
// ---------------------------------------------------------------------------
__global__ __launch_bounds__(64) void head_kernel(
    const float* __restrict__ hsf, const float* __restrict__ hsb,
    const float* __restrict__ fc1_w, const float* __restrict__ fc1_b,
    const float* __restrict__ fc2_w, const float* __restrict__ fc2_b,
    float* __restrict__ out)
{
    const int br = blockIdx.x;     // 0..159
    const int j = threadIdx.x;     // 0..63
    __shared__ float rev[HDIM];
    for (int e = j; e < HDIM; e += 64)
        rev[e] = 0.5f * (hsf[(size_t)br * HDIM + e] + hsb[(size_t)br * HDIM + e]);
    __syncthreads();
    float acc = 0.f;
    #pragma unroll
    for (int k = 0; k < HDIM; ++k)
        acc = fmaf(fc1_w[(size_t)j * HDIM + k], rev[k], acc);
    acc += fc1_b[j];
    const float alpha = 1.6732632423543772f;
    const float scale = 1.0507009873554805f;
    float h1 = scale * (acc > 0.f ? acc : alpha * (expf(acc) - 1.f));
    float contrib = h1 * fc2_w[j];
    #pragma unroll
    for (int off = 32; off > 0; off >>= 1)
        contrib += __shfl_down(contrib, off);
    if (j == 0) out[16 + br] = contrib + fc2_b[0];
}

// p_stars[b] = mean over r of r_stars[b, r]
__global__ void mean_kernel(float* __restrict__ out)
{
    int b = threadIdx.x;
    if (b < BB) {
        float s = 0.f;
        for (int r = 0; r < RR; ++r) s += out[16 + b * RR + r];
        out[b] = s / (float)RR;
    }
}

// ---------------------------------------------------------------------------
// Launch
// ---------------------------------------------------------------------------
extern "C" void kernel_launch(void* const* d_in, const int* in_sizes, int n_in,
                              void* d_out, int out_size, void* d_ws, size_t ws_size,
                              hipStream_t stream)
{
    const int*   inputs       = (const int*)d_in[0];
    const int*   sent_lengths = (const int*)d_in[1];
    const int*   sent_counts  = (const int*)d_in[2];
    const float* embed   = (const float*)d_in[3];
    const float* wWih_f  = (const float*)d_in[4];
    const float* wWhh_f  = (const float*)d_in[5];
    const float* wbih_f  = (const float*)d_in[6];
    const float* wbhh_f  = (const float*)d_in[7];
    const float* wWih_b  = (const float*)d_in[8];
    const float* wWhh_b  = (const float*)d_in[9];
    const float* wbih_b  = (const float*)d_in[10];
    const float* wbhh_b  = (const float*)d_in[11];
    const float* sWih_f  = (const float*)d_in[12];
    const float* sWhh_f  = (const float*)d_in[13];
    const float* sbih_f  = (const float*)d_in[14];
    const float* sbhh_f  = (const float*)d_in[15];
    const float* sWih_b  = (const float*)d_in[16];
    const float* sWhh_b  = (const float*)d_in[17];
    const float* sbih_b  = (const float*)d_in[18];
    const float* sbhh_b  = (const float*)d_in[19];
    const float* fc1_w   = (const float*)d_in[20];
    const float* fc1_b   = (const float*)d_in[21];
    const float* fc2_w   = (const float*)d_in[22];
    const float* fc2_b   = (const float*)d_in[23];

    float* ws = (float*)d_ws;
    // workspace layout (f32 elements)
    const size_t projT_elems = (size_t)VOCAB * NPROJ;      // 38,400,000
    const size_t xgs_elems   = (size_t)NSENT * NPROJ;      //  2,457,600
    const size_t h_elems     = (size_t)NSENT * HDIM;       //    409,600
    const size_t hs_elems    = (size_t)NREV * HDIM;        //     20,480
    float* projT = ws;
    float* xgs   = projT + projT_elems;
    float* hf    = xgs + xgs_elems;
    float* hb    = hf + h_elems;
    float* hsf   = hb + h_elems;
    float* hsb   = hsf + hs_elems;

    size_t need = (projT_elems + xgs_elems + 2*h_elems + 2*hs_elems) * sizeof(float);
    if (ws_size < need) return;   // cannot run without scratch

    // 1) projected-embedding table: projT[v] = [wWih_f; wWih_b] @ embed[v] + bih
    {
        dim3 grid(NPROJ / TS, (VOCAB + TS - 1) / TS);   // 12 x 782
        gemm2_bias<<<grid, 256, 0, stream>>>(
            embed, nullptr, VOCAB, EDIM,
            wWih_f, wWih_b, wbih_f, wbih_b, projT);
    }
    // 2) word-level BiGRU last-h: one (seq,dir) per block
    {
        gru_seq<true, WW><<<2 * NSENT, 384, 0, stream>>>(
            projT, inputs, sent_lengths,
            wWhh_f, wWhh_b, wbhh_f, wbhh_b,
            hf, hb, NSENT);
    }
    // 3) sentence-level input projections: xgs = (0.5*(hf+hb)) @ [sWih_f;sWih_b]^T + sbih
    {
        dim3 grid(NPROJ / TS, NSENT / TS);              // 12 x 50
        gemm2_bias<<<grid, 256, 0, stream>>>(
            hf, hb, NSENT, HDIM,
            sWih_f, sWih_b, sbih_f, sbih_b, xgs);
    }
    // 4) sentence-level BiGRU last-h
    {
        gru_seq<false, SS><<<2 * NREV, 384, 0, stream>>>(
            xgs, nullptr, sent_counts,
            sWhh_f, sWhh_b, sbhh_f, sbhh_b,
            hsf, hsb, NREV);
    }
    // 5) FC head -> r_stars, then p_stars
    head_kernel<<<NREV, 64, 0, stream>>>(hsf, hsb, fc1_w, fc1_b, fc2_w, fc2_b,
                                         (float*)d_out);
    mean_kernel<<<1, 64, 0, stream>>>((float*)d_out);
}

// Round 4
// 962.715 us; speedup vs baseline: 1.5345x; 1.5345x over previous
//
#include <hip/hip_runtime.h>
#include <hip/hip_bf16.h>
#include <cstddef>

// ---------------------------------------------------------------------------
// Problem dims (compile-time constants from the reference)
// ---------------------------------------------------------------------------
#define VOCAB 50000
#define EDIM  200
#define HDIM  128
#define BB 16
#define RR 10
#define SS 20
#define WW 64
#define NSENT (BB*RR*SS)   // 3200 word-level sequences
#define NREV  (BB*RR)      // 160 sentence-level sequences
#define G3    (3*HDIM)     // 384 gate rows per direction
#define NPROJ (2*G3)       // 768 (fwd+bwd concatenated)

// ---------------------------------------------------------------------------
// Generic tiled f32 GEMM:  C[M x 768] = A[M x K] @ [B0;B1]^T + [bias0;bias1]
// ---------------------------------------------------------------------------
#define TS 64
#define KC 32

__global__ __launch_bounds__(256) void gemm2_bias(
    const float* __restrict__ A0, const float* __restrict__ A1,
    int M, int K,
    const float* __restrict__ B0, const float* __restrict__ B1,
    const float* __restrict__ bias0, const float* __restrict__ bias1,
    float* __restrict__ C)
{
    __shared__ __align__(16) float At[KC][TS + 4];
    __shared__ __align__(16) float Bt[KC][TS + 4];

    const int ct = blockIdx.x;            // col tiles over 768
    const int rt = blockIdx.y;            // row tiles over M
    const int tid = threadIdx.x;
    const int r0 = (tid >> 4) << 2;
    const int c0 = (tid & 15) << 2;
    const int rowBase = rt * TS;
    const int colBase = ct * TS;

    const float* Bsrc = (colBase < G3) ? B0 : B1;
    const int bcolBase = (colBase < G3) ? colBase : (colBase - G3);

    float acc[4][4];
    #pragma unroll
    for (int i = 0; i < 4; ++i)
        #pragma unroll
        for (int j = 0; j < 4; ++j) acc[i][j] = 0.f;

    for (int k0 = 0; k0 < K; k0 += KC) {
        const int kc = min(KC, K - k0);
        for (int f = tid; f < TS * KC; f += 256) {
            int r = f >> 5;
            int k = f & 31;
            float v = 0.f;
            int row = rowBase + r;
            if (k < kc && row < M) {
                size_t idx = (size_t)row * K + k0 + k;
                v = A0[idx];
                if (A1) v = 0.5f * (v + A1[idx]);
            }
            At[k][r] = v;
        }
        for (int f = tid; f < TS * KC; f += 256) {
            int r = f >> 5;
            int k = f & 31;
            float v = 0.f;
            if (k < kc) v = Bsrc[(size_t)(bcolBase + r) * K + k0 + k];
            Bt[k][r] = v;
        }
        __syncthreads();
        #pragma unroll 8
        for (int k = 0; k < kc; ++k) {
            float4 av = *(const float4*)&At[k][r0];
            float4 bv = *(const float4*)&Bt[k][c0];
            acc[0][0] = fmaf(av.x, bv.x, acc[0][0]);
            acc[0][1] = fmaf(av.x, bv.y, acc[0][1]);
            acc[0][2] = fmaf(av.x, bv.z, acc[0][2]);
            acc[0][3] = fmaf(av.x, bv.w, acc[0][3]);
            acc[1][0] = fmaf(av.y, bv.x, acc[1][0]);
            acc[1][1] = fmaf(av.y, bv.y, acc[1][1]);
            acc[1][2] = fmaf(av.y, bv.z, acc[1][2]);
            acc[1][3] = fmaf(av.y, bv.w, acc[1][3]);
            acc[2][0] = fmaf(av.z, bv.x, acc[2][0]);
            acc[2][1] = fmaf(av.z, bv.y, acc[2][1]);
            acc[2][2] = fmaf(av.z, bv.z, acc[2][2]);
            acc[2][3] = fmaf(av.z, bv.w, acc[2][3]);
            acc[3][0] = fmaf(av.w, bv.x, acc[3][0]);
            acc[3][1] = fmaf(av.w, bv.y, acc[3][1]);
            acc[3][2] = fmaf(av.w, bv.z, acc[3][2]);
            acc[3][3] = fmaf(av.w, bv.w, acc[3][3]);
        }
        __syncthreads();
    }

    const float* bsrc = (colBase < G3) ? bias0 : bias1;
    #pragma unroll
    for (int i = 0; i < 4; ++i) {
        int row = rowBase + r0 + i;
        if (row < M) {
            float* cp = C + (size_t)row * NPROJ + colBase + c0;
            #pragma unroll
            for (int j = 0; j < 4; ++j)
                cp[j] = acc[i][j] + bsrc[bcolBase + c0 + j];
        }
    }
}

// ---------------------------------------------------------------------------
// Counting sort by length (64 buckets). Order within a bucket is race-
// dependent but every sequence's result is computed independently and
// written to its own slot -> final output is deterministic.
// ---------------------------------------------------------------------------
__global__ void sort_init(int* hist) {
    if (threadIdx.x < 65) hist[threadIdx.x] = 0;
}
__global__ void sort_hist(const int* __restrict__ lengths, int n, int* hist) {
    int i = blockIdx.x * 256 + threadIdx.x;
    if (i < n) atomicAdd(&hist[lengths[i]], 1);
}
__global__ void sort_scan(int* hist, int maxlen) {
    if (threadIdx.x == 0) {
        int acc = 0;
        for (int l = 1; l <= maxlen; ++l) { int c = hist[l]; hist[l] = acc; acc += c; }
    }
}
__global__ void sort_scatter(const int* __restrict__ lengths, int n,
                             int* hist, int* order) {
    int i = blockIdx.x * 256 + threadIdx.x;
    if (i < n) {
        int pos = atomicAdd(&hist[lengths[i]], 1);
        order[pos] = i;
    }
}

// ---------------------------------------------------------------------------
// GRU scan kernel, k-split-2 layout, sorted tiles.
// Grid: 2*numTiles blocks (first half dir=fwd, second half dir=bwd).
// Block: 768 threads = (row o in [0,384)) x (k-half in {0,1}).
// Tile i covers sorted positions [i*NSEQ, i*NSEQ+NSEQ) of `order` ->
// near-equal lengths -> minimal max-len waste. Tiles dispatched longest-
// first. xg gather for step t is prefetched before the matvec.
// ---------------------------------------------------------------------------
template<int NSEQ, bool WORD, int TMAX>
__global__ __launch_bounds__(768, 3) void gru_scan(
    const float* __restrict__ table,    // [*, 768] projected-input table
    const int*   __restrict__ tokens,   // word-level: [numSeq*WW]; else unused
    const int*   __restrict__ lengths,  // [numSeq]
    const int*   __restrict__ order,    // [numSeq] sorted-by-length indices
    const float* __restrict__ Whh_f, const float* __restrict__ Whh_b,
    const float* __restrict__ bhh_f, const float* __restrict__ bhh_b,
    float* __restrict__ hout_f, float* __restrict__ hout_b,
    int numSeq, int numTiles)
{
    const int dir  = (blockIdx.x >= numTiles) ? 1 : 0;
    const int rawt = dir ? (blockIdx.x - numTiles) : blockIdx.x;
    const int tile = numTiles - 1 - rawt;    // longest tiles first
    const int base = tile * NSEQ;
    const int tid = threadIdx.x;        // 0..767
    const int half = (tid >= 384) ? 1 : 0;   // wave-uniform (384 = 6*64)
    const int o = tid - half * 384;     // 0..383

    const float* Whh = dir ? Whh_b : Whh_f;
    float w[64];
    #pragma unroll
    for (int i = 0; i < 16; ++i) {
        float4 v = *(const float4*)(Whh + (size_t)o * HDIM + half * 64 + i * 4);
        w[4*i+0] = v.x; w[4*i+1] = v.y; w[4*i+2] = v.z; w[4*i+3] = v.w;
    }
    const float bhh_r = half ? 0.f : (dir ? bhh_b : bhh_f)[o];

    __shared__ __align__(16) float sh_h[NSEQ][HDIM];
    __shared__ float sh_hgp[2][NSEQ][G3];
    __shared__ int sh_len[NSEQ];
    __shared__ int sh_ord[NSEQ];
    __shared__ int sh_tok[WORD ? NSEQ * WW : 1];

    if (tid < NSEQ) {
        int pos = base + tid;
        int seq = (pos < numSeq) ? order[pos] : -1;
        sh_ord[tid] = seq;
        sh_len[tid] = (seq >= 0) ? lengths[seq] : 0;
    }
    __syncthreads();
    if (WORD) {
        for (int f = tid; f < NSEQ * WW; f += 768) {
            int s = f / WW;
            int seq = sh_ord[s];
            sh_tok[f] = (seq >= 0) ? tokens[(size_t)seq * WW + (f % WW)] : 0;
        }
    }
    for (int u = tid; u < NSEQ * HDIM; u += 768)
        sh_h[u >> 7][u & 127] = 0.f;
    __syncthreads();

    // per-thread copies of lengths (constant indices after unroll -> regs)
    int lenreg[NSEQ];
    int maxlen = 0;
    #pragma unroll
    for (int s = 0; s < NSEQ; ++s) {
        lenreg[s] = sh_len[s];
        maxlen = max(maxlen, lenreg[s]);
    }

    // gate-phase mapping: exactly one (seq, elem) per thread (NSEQ*128 == 768)
    const int s_g = tid >> 7;           // 0..NSEQ-1
    const int e_g = tid & 127;
    const int len_g = sh_len[s_g];
    const int ord_g = sh_ord[s_g];

    for (int t = 0; t < maxlen; ++t) {
        // ---- prefetch this step's xg gather into registers ----
        float pr = 0.f, pz = 0.f, pn = 0.f;
        const bool act_g = (t < len_g);
        if (act_g) {
            int tt = dir ? (len_g - 1 - t) : t;
            size_t row;
            if (WORD) row = (size_t)sh_tok[s_g * WW + tt];
            else      row = (size_t)ord_g * TMAX + tt;
            const float* xg = table + row * NPROJ + dir * G3 + e_g;
            pr = xg[0]; pz = xg[HDIM]; pn = xg[2*HDIM];
        }
        // ---- hg partial: half-dot over 64 h-elems, per active sequence ----
        #pragma unroll
        for (int s = 0; s < NSEQ; ++s) {
            if (t < lenreg[s]) {        // wave-uniform branch
                const float4* h4 = (const float4*)(&sh_h[s][half * 64]);
                float a0 = 0.f, a1 = 0.f, a2 = 0.f, a3 = 0.f;
                #pragma unroll
                for (int i = 0; i < 16; ++i) {
                    float4 hv = h4[i];
                    a0 = fmaf(w[4*i+0], hv.x, a0);
                    a1 = fmaf(w[4*i+1], hv.y, a1);
                    a2 = fmaf(w[4*i+2], hv.z, a2);
                    a3 = fmaf(w[4*i+3], hv.w, a3);
                }
                sh_hgp[half][s][o] = ((a0 + a1) + (a2 + a3)) + bhh_r;
            }
        }
        __syncthreads();
        // ---- gate update: one (seq, elem) per thread ----
        if (act_g) {
            float hgr = sh_hgp[0][s_g][e_g]          + sh_hgp[1][s_g][e_g];
            float hgz = sh_hgp[0][s_g][e_g + HDIM]   + sh_hgp[1][s_g][e_g + HDIM];
            float hgn = sh_hgp[0][s_g][e_g + 2*HDIM] + sh_hgp[1][s_g][e_g + 2*HDIM];
            float hold = sh_h[s_g][e_g];
            float r = 1.f / (1.f + expf(-(pr + hgr)));
            float z = 1.f / (1.f + expf(-(pz + hgz)));
            float n = tanhf(pn + r * hgn);
            sh_h[s_g][e_g] = (1.f - z) * n + z * hold;
        }
        __syncthreads();
    }

    float* hout = dir ? hout_b : hout_f;
    for (int u = tid; u < NSEQ * HDIM; u += 768) {
        int s = u >> 7, e = u & 127;
        int seq = sh_ord[s];
        if (seq >= 0) hout[(size_t)seq * HDIM + e] = sh_h[s][e];
    }
}

// ---------------------------------------------------------------------------
// Head: rev = 0.5*(hsf+hsb); h1 = selu(rev @ fc1^T + b1); r = h1 @ fc2^T + b2
// ---------------------------------------------------------------------------
__global__ __launch_bounds__(64) void head_kernel(
    const float* __restrict__ hsf, const float* __restrict__ hsb,
    const float* __restrict__ fc1_w, const float* __restrict__ fc1_b,
    const float* __restrict__ fc2_w, const float* __restrict__ fc2_b,
    float* __restrict__ out)
{
    const int br = blockIdx.x;     // 0..159
    const int j = threadIdx.x;     // 0..63
    __shared__ float rev[HDIM];
    for (int e = j; e < HDIM; e += 64)
        rev[e] = 0.5f * (hsf[(size_t)br * HDIM + e] + hsb[(size_t)br * HDIM + e]);
    __syncthreads();
    float acc = 0.f;
    #pragma unroll
    for (int k = 0; k < HDIM; ++k)
        acc = fmaf(fc1_w[(size_t)j * HDIM + k], rev[k], acc);
    acc += fc1_b[j];
    const float alpha = 1.6732632423543772f;
    const float scale = 1.0507009873554805f;
    float h1 = scale * (acc > 0.f ? acc : alpha * (expf(acc) - 1.f));
    float contrib = h1 * fc2_w[j];
    #pragma unroll
    for (int off = 32; off > 0; off >>= 1)
        contrib += __shfl_down(contrib, off);
    if (j == 0) out[16 + br] = contrib + fc2_b[0];
}

// p_stars[b] = mean over r of r_stars[b, r]
__global__ void mean_kernel(float* __restrict__ out)
{
    int b = threadIdx.x;
    if (b < BB) {
        float s = 0.f;
        for (int r = 0; r < RR; ++r) s += out[16 + b * RR + r];
        out[b] = s / (float)RR;
    }
}

// ---------------------------------------------------------------------------
// Launch
// ---------------------------------------------------------------------------
extern "C" void kernel_launch(void* const* d_in, const int* in_sizes, int n_in,
                              void* d_out, int out_size, void* d_ws, size_t ws_size,
                              hipStream_t stream)
{
    const int*   inputs       = (const int*)d_in[0];
    const int*   sent_lengths = (const int*)d_in[1];
    const int*   sent_counts  = (const int*)d_in[2];
    const float* embed   = (const float*)d_in[3];
    const float* wWih_f  = (const float*)d_in[4];
    const float* wWhh_f  = (const float*)d_in[5];
    const float* wbih_f  = (const float*)d_in[6];
    const float* wbhh_f  = (const float*)d_in[7];
    const float* wWih_b  = (const float*)d_in[8];
    const float* wWhh_b  = (const float*)d_in[9];
    const float* wbih_b  = (const float*)d_in[10];
    const float* wbhh_b  = (const float*)d_in[11];
    const float* sWih_f  = (const float*)d_in[12];
    const float* sWhh_f  = (const float*)d_in[13];
    const float* sbih_f  = (const float*)d_in[14];
    const float* sbhh_f  = (const float*)d_in[15];
    const float* sWih_b  = (const float*)d_in[16];
    const float* sWhh_b  = (const float*)d_in[17];
    const float* sbih_b  = (const float*)d_in[18];
    const float* sbhh_b  = (const float*)d_in[19];
    const float* fc1_w   = (const float*)d_in[20];
    const float* fc1_b   = (const float*)d_in[21];
    const float* fc2_w   = (const float*)d_in[22];
    const float* fc2_b   = (const float*)d_in[23];

    float* ws = (float*)d_ws;
    // workspace layout (f32 elements)
    const size_t projT_elems = (size_t)VOCAB * NPROJ;      // 38,400,000
    const size_t xgs_elems   = (size_t)NSENT * NPROJ;      //  2,457,600
    const size_t h_elems     = (size_t)NSENT * HDIM;       //    409,600
    const size_t hs_elems    = (size_t)NREV * HDIM;        //     20,480
    float* projT = ws;
    float* xgs   = projT + projT_elems;
    float* hf    = xgs + xgs_elems;
    float* hb    = hf + h_elems;
    float* hsf   = hb + h_elems;
    float* hsb   = hsf + hs_elems;
    int* order1 = (int*)(hsb + hs_elems);          // [NSENT]
    int* hist1  = order1 + NSENT;                  // [65]
    int* order2 = hist1 + 65;                      // [NREV]
    int* hist2  = order2 + NREV;                   // [65]

    size_t need = (projT_elems + xgs_elems + 2*h_elems + 2*hs_elems) * sizeof(float)
                + (NSENT + NREV + 130) * sizeof(int);
    if (ws_size < need) return;   // cannot run without scratch

    // 0) counting sort of both length arrays (tiny kernels)
    sort_init<<<1, 65, 0, stream>>>(hist1);
    sort_init<<<1, 65, 0, stream>>>(hist2);
    sort_hist<<<(NSENT + 255) / 256, 256, 0, stream>>>(sent_lengths, NSENT, hist1);
    sort_hist<<<(NREV + 255) / 256, 256, 0, stream>>>(sent_counts, NREV, hist2);
    sort_scan<<<1, 1, 0, stream>>>(hist1, WW);
    sort_scan<<<1, 1, 0, stream>>>(hist2, SS);
    sort_scatter<<<(NSENT + 255) / 256, 256, 0, stream>>>(sent_lengths, NSENT, hist1, order1);
    sort_scatter<<<(NREV + 255) / 256, 256, 0, stream>>>(sent_counts, NREV, hist2, order2);

    // 1) projected-embedding table: projT[v] = [wWih_f; wWih_b] @ embed[v] + bih
    {
        dim3 grid(NPROJ / TS, (VOCAB + TS - 1) / TS);   // 12 x 782
        gemm2_bias<<<grid, 256, 0, stream>>>(
            embed, nullptr, VOCAB, EDIM,
            wWih_f, wWih_b, wbih_f, wbih_b, projT);
    }
    // 2) word-level BiGRU last-h (sorted tiles)
    {
        constexpr int NSEQ = 6;
        int numTiles = (NSENT + NSEQ - 1) / NSEQ;       // 534
        gru_scan<NSEQ, true, WW><<<2 * numTiles, 768, 0, stream>>>(
            projT, inputs, sent_lengths, order1,
            wWhh_f, wWhh_b, wbhh_f, wbhh_b,
            hf, hb, NSENT, numTiles);
    }
    // 3) sentence-level input projections: xgs = (0.5*(hf+hb)) @ [sWih_f;sWih_b]^T + sbih
    {
        dim3 grid(NPROJ / TS, NSENT / TS);              // 12 x 50
        gemm2_bias<<<grid, 256, 0, stream>>>(
            hf, hb, NSENT, HDIM,
            sWih_f, sWih_b, sbih_f, sbih_b, xgs);
    }
    // 4) sentence-level BiGRU last-h (sorted tiles)
    {
        constexpr int NSEQ = 6;
        int numTiles = (NREV + NSEQ - 1) / NSEQ;        // 27
        gru_scan<NSEQ, false, SS><<<2 * numTiles, 768, 0, stream>>>(
            xgs, nullptr, sent_counts, order2,
            sWhh_f, sWhh_b, sbhh_f, sbhh_b,
            hsf, hsb, NREV, numTiles);
    }
    // 5) FC head -> r_stars, then p_stars
    head_kernel<<<NREV, 64, 0, stream>>>(hsf, hsb, fc1_w, fc1_b, fc2_w, fc2_b,
                                         (float*)d_out);
    mean_kernel<<<1, 64, 0, stream>>>((float*)d_out);
}

// Round 5
// 592.009 us; speedup vs baseline: 2.4954x; 1.6262x over previous
//
#include <hip/hip_runtime.h>
#include <hip/hip_bf16.h>
#include <cstddef>

// ---------------------------------------------------------------------------
// Problem dims
// ---------------------------------------------------------------------------
#define VOCAB 50000
#define EDIM  200
#define HDIM  128
#define BB 16
#define RR 10
#define SS 20
#define WW 64
#define NSENT (BB*RR*SS)   // 3200 word-level sequences
#define NREV  (BB*RR)      // 160 sentence-level sequences
#define G3    (3*HDIM)     // 384 gate rows per direction
#define NPROJ (2*G3)       // 768

// ---------------------------------------------------------------------------
// Generic tiled f32 GEMM:  C[M x 768] = A[M x K] @ [B0;B1]^T + [bias0;bias1]
// ---------------------------------------------------------------------------
#define TS 64
#define KC 32

__global__ __launch_bounds__(256) void gemm2_bias(
    const float* __restrict__ A0, const float* __restrict__ A1,
    int M, int K,
    const float* __restrict__ B0, const float* __restrict__ B1,
    const float* __restrict__ bias0, const float* __restrict__ bias1,
    float* __restrict__ C)
{
    __shared__ __align__(16) float At[KC][TS + 4];
    __shared__ __align__(16) float Bt[KC][TS + 4];

    const int ct = blockIdx.x;
    const int rt = blockIdx.y;
    const int tid = threadIdx.x;
    const int r0 = (tid >> 4) << 2;
    const int c0 = (tid & 15) << 2;
    const int rowBase = rt * TS;
    const int colBase = ct * TS;

    const float* Bsrc = (colBase < G3) ? B0 : B1;
    const int bcolBase = (colBase < G3) ? colBase : (colBase - G3);

    float acc[4][4];
    #pragma unroll
    for (int i = 0; i < 4; ++i)
        #pragma unroll
        for (int j = 0; j < 4; ++j) acc[i][j] = 0.f;

    for (int k0 = 0; k0 < K; k0 += KC) {
        const int kc = min(KC, K - k0);
        for (int f = tid; f < TS * KC; f += 256) {
            int r = f >> 5;
            int k = f & 31;
            float v = 0.f;
            int row = rowBase + r;
            if (k < kc && row < M) {
                size_t idx = (size_t)row * K + k0 + k;
                v = A0[idx];
                if (A1) v = 0.5f * (v + A1[idx]);
            }
            At[k][r] = v;
        }
        for (int f = tid; f < TS * KC; f += 256) {
            int r = f >> 5;
            int k = f & 31;
            float v = 0.f;
            if (k < kc) v = Bsrc[(size_t)(bcolBase + r) * K + k0 + k];
            Bt[k][r] = v;
        }
        __syncthreads();
        #pragma unroll 8
        for (int k = 0; k < kc; ++k) {
            float4 av = *(const float4*)&At[k][r0];
            float4 bv = *(const float4*)&Bt[k][c0];
            acc[0][0] = fmaf(av.x, bv.x, acc[0][0]);
            acc[0][1] = fmaf(av.x, bv.y, acc[0][1]);
            acc[0][2] = fmaf(av.x, bv.z, acc[0][2]);
            acc[0][3] = fmaf(av.x, bv.w, acc[0][3]);
            acc[1][0] = fmaf(av.y, bv.x, acc[1][0]);
            acc[1][1] = fmaf(av.y, bv.y, acc[1][1]);
            acc[1][2] = fmaf(av.y, bv.z, acc[1][2]);
            acc[1][3] = fmaf(av.y, bv.w, acc[1][3]);
            acc[2][0] = fmaf(av.z, bv.x, acc[2][0]);
            acc[2][1] = fmaf(av.z, bv.y, acc[2][1]);
            acc[2][2] = fmaf(av.z, bv.z, acc[2][2]);
            acc[2][3] = fmaf(av.z, bv.w, acc[2][3]);
            acc[3][0] = fmaf(av.w, bv.x, acc[3][0]);
            acc[3][1] = fmaf(av.w, bv.y, acc[3][1]);
            acc[3][2] = fmaf(av.w, bv.z, acc[3][2]);
            acc[3][3] = fmaf(av.w, bv.w, acc[3][3]);
        }
        __syncthreads();
    }

    const float* bsrc = (colBase < G3) ? bias0 : bias1;
    #pragma unroll
    for (int i = 0; i < 4; ++i) {
        int row = rowBase + r0 + i;
        if (row < M) {
            float* cp = C + (size_t)row * NPROJ + colBase + c0;
            #pragma unroll
            for (int j = 0; j < 4; ++j)
                cp[j] = acc[i][j] + bsrc[bcolBase + c0 + j];
        }
    }
}

// ---------------------------------------------------------------------------
// Counting sort by length (order within bucket race-dependent; results are
// written per-sequence so final output is deterministic).
// ---------------------------------------------------------------------------
__global__ void sort_init(int* hist) {
    if (threadIdx.x < 65) hist[threadIdx.x] = 0;
}
__global__ void sort_hist(const int* __restrict__ lengths, int n, int* hist) {
    int i = blockIdx.x * 256 + threadIdx.x;
    if (i < n) atomicAdd(&hist[lengths[i]], 1);
}
__global__ void sort_scan(int* hist, int maxlen) {
    if (threadIdx.x == 0) {
        int acc = 0;
        for (int l = 1; l <= maxlen; ++l) { int c = hist[l]; hist[l] = acc; acc += c; }
    }
}
__global__ void sort_scatter(const int* __restrict__ lengths, int n,
                             int* hist, int* order) {
    int i = blockIdx.x * 256 + threadIdx.x;
    if (i < n) {
        int pos = atomicAdd(&hist[lengths[i]], 1);
        order[pos] = i;
    }
}

// ---------------------------------------------------------------------------
// bf16 helpers (RNE via bit trick; no API dependence)
// ---------------------------------------------------------------------------
static __device__ __forceinline__ short f2bf(float f) {
    union { float f; unsigned u; } v; v.f = f;
    unsigned r = v.u + 0x7FFFu + ((v.u >> 16) & 1u);
    return (short)(r >> 16);
}
static __device__ __forceinline__ float bf2f(short s) {
    union { unsigned u; float f; } v;
    v.u = ((unsigned)(unsigned short)s) << 16;
    return v.f;
}
static __device__ __forceinline__ float fsigmoid(float x) {
    return 1.f / (1.f + __expf(-x));
}
static __device__ __forceinline__ float ftanh(float x) {
    float xc = fminf(fmaxf(x, -15.f), 15.f);
    float e = __expf(-2.f * xc);
    return (1.f - e) / (1.f + e);
}

// ---------------------------------------------------------------------------
// MFMA GRU scan. One block = one (tile of 16 sorted sequences, direction).
// 512 threads = 8 waves. Per step: hg(16x384) = h(16x128) @ Whh^T via
// split-bf16 MFMA (D = Ah*Bh + Ah*Bl + Al*Bh, err ~2^-22), weights held
// fragment-resident in VGPRs (wave w owns gate cols [48w,48w+48)).
// Layouts (m91-verified): A/B frag lane l: row/col=l&15, k=(l>>4)*8+j;
// C/D: col=lane&15, row(seq)=(lane>>4)*4+reg.
// Gate phase: thread -> (e=tid&127, seqs {tid>>7 + 4j}), f32 scalar.
// ---------------------------------------------------------------------------
template<bool WORD, int TMAX>
__global__ __launch_bounds__(512, 2) void gru_mfma(
    const float* __restrict__ table,    // [*, 768] projected-input table
    const int*   __restrict__ tokens,   // word-level: [numSeq*WW]
    const int*   __restrict__ lengths,  // [numSeq]
    const int*   __restrict__ order,    // [numSeq] sorted-by-length indices
    const float* __restrict__ Whh_f, const float* __restrict__ Whh_b,
    const float* __restrict__ bhh_f, const float* __restrict__ bhh_b,
    float* __restrict__ hout_f, float* __restrict__ hout_b,
    int numSeq, int numTiles)
{
    using bf16x8 = __attribute__((ext_vector_type(8))) short;
    using f32x4  = __attribute__((ext_vector_type(4))) float;

    const int dir  = (blockIdx.x >= numTiles) ? 1 : 0;
    const int rawt = dir ? (blockIdx.x - numTiles) : blockIdx.x;
    const int tile = numTiles - 1 - rawt;      // longest tiles first
    const int base = tile * 16;
    const int tid  = threadIdx.x;              // 0..511
    const int lane = tid & 63;
    const int wid  = tid >> 6;                 // 0..7
    const int rlane = lane & 15;
    const int kgrp  = lane >> 4;               // 0..3

    __shared__ __align__(16) float sh_h[16][132];   // padded (bank spread)
    __shared__ float sh_hg[16][388];                // padded (2-way max)
    __shared__ int sh_len[16];
    __shared__ int sh_ord[16];
    __shared__ int sh_tok[WORD ? 16 * WW : 1];
    __shared__ int sh_maxlen;

    // ---- per-wave weight fragments (persist whole kernel) ----
    const float* Whh = dir ? Whh_b : Whh_f;
    const float* bhh = dir ? bhh_b : bhh_f;
    bf16x8 Bhi[3][4], Blo[3][4];
    float bb[3];
    #pragma unroll
    for (int nt = 0; nt < 3; ++nt) {
        const int cb = (3 * wid + nt) * 16;
        const float* wrow = Whh + (size_t)(cb + rlane) * HDIM;
        bb[nt] = bhh[cb + rlane];
        #pragma unroll
        for (int kc = 0; kc < 4; ++kc) {
            const float* wp = wrow + kc * 32 + kgrp * 8;
            float4 w0 = *(const float4*)wp;
            float4 w1 = *(const float4*)(wp + 4);
            float wv[8] = {w0.x, w0.y, w0.z, w0.w, w1.x, w1.y, w1.z, w1.w};
            #pragma unroll
            for (int j = 0; j < 8; ++j) {
                short hi = f2bf(wv[j]);
                Bhi[nt][kc][j] = hi;
                Blo[nt][kc][j] = f2bf(wv[j] - bf2f(hi));
            }
        }
    }

    // ---- tile metadata + state init ----
    if (tid < 16) {
        int pos = base + tid;
        int seq = (pos < numSeq) ? order[pos] : -1;
        sh_ord[tid] = seq;
        sh_len[tid] = (seq >= 0) ? lengths[seq] : 0;
    }
    __syncthreads();
    if (WORD) {
        for (int f = tid; f < 16 * WW; f += 512) {
            int s = f >> 6;
            int seq = sh_ord[s];
            sh_tok[f] = (seq >= 0) ? tokens[(size_t)seq * WW + (f & 63)] : 0;
        }
    }
    for (int u = tid; u < 16 * HDIM; u += 512)
        sh_h[u >> 7][u & 127] = 0.f;
    if (tid == 0) {
        int m = 0;
        for (int s = 0; s < 16; ++s) m = max(m, sh_len[s]);
        sh_maxlen = m;
    }
    // gate-phase per-thread regs (sh_len/sh_ord stable after first barrier)
    const int s0 = tid >> 7;          // 0..3
    const int e  = tid & 127;
    int glen[4], gord[4];
    #pragma unroll
    for (int j = 0; j < 4; ++j) {
        glen[j] = sh_len[s0 + 4 * j];
        gord[j] = sh_ord[s0 + 4 * j];
    }
    __syncthreads();
    const int maxlen = sh_maxlen;

    // ---- xg gather (3 f32 per (seq,e)); prefetched one step ahead ----
    auto fetch_xg = [&](int t, float* fr, float* fz, float* fn) {
        #pragma unroll
        for (int j = 0; j < 4; ++j) {
            fr[j] = 0.f; fz[j] = 0.f; fn[j] = 0.f;
            if (t < glen[j]) {
                int tt = dir ? (glen[j] - 1 - t) : t;
                size_t row;
                if (WORD) row = (size_t)sh_tok[(s0 + 4 * j) * WW + tt];
                else      row = (size_t)gord[j] * TMAX + tt;
                const float* xg = table + row * NPROJ + dir * G3 + e;
                fr[j] = xg[0]; fz[j] = xg[HDIM]; fn[j] = xg[2 * HDIM];
            }
        }
    };

    float pr[4], pz[4], pn[4];
    fetch_xg(0, pr, pz, pn);

    for (int t = 0; t < maxlen; ++t) {
        // ---- A fragments from current h (all waves redundantly) ----
        bf16x8 Ahi[4], Alo[4];
        #pragma unroll
        for (int kc = 0; kc < 4; ++kc) {
            const float* hp = &sh_h[rlane][kc * 32 + kgrp * 8];
            float4 h0 = *(const float4*)hp;
            float4 h1 = *(const float4*)(hp + 4);
            float hv[8] = {h0.x, h0.y, h0.z, h0.w, h1.x, h1.y, h1.z, h1.w};
            #pragma unroll
            for (int j = 0; j < 8; ++j) {
                short hi = f2bf(hv[j]);
                Ahi[kc][j] = hi;
                Alo[kc][j] = f2bf(hv[j] - bf2f(hi));
            }
        }
        // ---- split-bf16 MFMA: acc = Ah*Bh + Ah*Bl + Al*Bh ----
        f32x4 acc[3];
        #pragma unroll
        for (int nt = 0; nt < 3; ++nt) {
            acc[nt] = {0.f, 0.f, 0.f, 0.f};
            #pragma unroll
            for (int kc = 0; kc < 4; ++kc)
                acc[nt] = __builtin_amdgcn_mfma_f32_16x16x32_bf16(
                    Ahi[kc], Bhi[nt][kc], acc[nt], 0, 0, 0);
            #pragma unroll
            for (int kc = 0; kc < 4; ++kc)
                acc[nt] = __builtin_amdgcn_mfma_f32_16x16x32_bf16(
                    Ahi[kc], Blo[nt][kc], acc[nt], 0, 0, 0);
            #pragma unroll
            for (int kc = 0; kc < 4; ++kc)
                acc[nt] = __builtin_amdgcn_mfma_f32_16x16x32_bf16(
                    Alo[kc], Bhi[nt][kc], acc[nt], 0, 0, 0);
        }
        // ---- unload hg (+bias) to LDS; D: col=lane&15, row(seq)=kgrp*4+r ----
        #pragma unroll
        for (int nt = 0; nt < 3; ++nt) {
            const int cb = (3 * wid + nt) * 16;
            #pragma unroll
            for (int r = 0; r < 4; ++r)
                sh_hg[kgrp * 4 + r][cb + rlane] = acc[nt][r] + bb[nt];
        }
        // ---- prefetch next step's xg (hides under gate phase) ----
        float qr[4], qz[4], qn[4];
        fetch_xg(t + 1, qr, qz, qn);
        __syncthreads();
        // ---- gate update: 4 (seq, e) pairs per thread ----
        #pragma unroll
        for (int j = 0; j < 4; ++j) {
            if (t < glen[j]) {
                int s = s0 + 4 * j;
                float hgr = sh_hg[s][e];
                float hgz = sh_hg[s][e + HDIM];
                float hgn = sh_hg[s][e + 2 * HDIM];
                float hold = sh_h[s][e];
                float rg = fsigmoid(pr[j] + hgr);
                float zg = fsigmoid(pz[j] + hgz);
                float ng = ftanh(pn[j] + rg * hgn);
                sh_h[s][e] = (1.f - zg) * ng + zg * hold;
            }
        }
        __syncthreads();
        #pragma unroll
        for (int j = 0; j < 4; ++j) { pr[j] = qr[j]; pz[j] = qz[j]; pn[j] = qn[j]; }
    }

    // ---- write out last-h ----
    float* hout = dir ? hout_b : hout_f;
    for (int u = tid; u < 16 * HDIM; u += 512) {
        int s = u >> 7, ee = u & 127;
        int seq = sh_ord[s];
        if (seq >= 0) hout[(size_t)seq * HDIM + ee] = sh_h[s][ee];
    }
}

// ---------------------------------------------------------------------------
// Head: rev = 0.5*(hsf+hsb); h1 = selu(rev @ fc1^T + b1); r = h1 @ fc2^T + b2
// ---------------------------------------------------------------------------
__global__ __launch_bounds__(64) void head_kernel(
    const float* __restrict__ hsf, const float* __restrict__ hsb,
    const float* __restrict__ fc1_w, const float* __restrict__ fc1_b,
    const float* __restrict__ fc2_w, const float* __restrict__ fc2_b,
    float* __restrict__ out)
{
    const int br = blockIdx.x;
    const int j = threadIdx.x;
    __shared__ float rev[HDIM];
    for (int ee = j; ee < HDIM; ee += 64)
        rev[ee] = 0.5f * (hsf[(size_t)br * HDIM + ee] + hsb[(size_t)br * HDIM + ee]);
    __syncthreads();
    float acc = 0.f;
    #pragma unroll
    for (int k = 0; k < HDIM; ++k)
        acc = fmaf(fc1_w[(size_t)j * HDIM + k], rev[k], acc);
    acc += fc1_b[j];
    const float alpha = 1.6732632423543772f;
    const float scale = 1.0507009873554805f;
    float h1 = scale * (acc > 0.f ? acc : alpha * (expf(acc) - 1.f));
    float contrib = h1 * fc2_w[j];
    #pragma unroll
    for (int off = 32; off > 0; off >>= 1)
        contrib += __shfl_down(contrib, off);
    if (j == 0) out[16 + br] = contrib + fc2_b[0];
}

__global__ void mean_kernel(float* __restrict__ out)
{
    int b = threadIdx.x;
    if (b < BB) {
        float s = 0.f;
        for (int r = 0; r < RR; ++r) s += out[16 + b * RR + r];
        out[b] = s / (float)RR;
    }
}

// ---------------------------------------------------------------------------
// Launch
// ---------------------------------------------------------------------------
extern "C" void kernel_launch(void* const* d_in, const int* in_sizes, int n_in,
                              void* d_out, int out_size, void* d_ws, size_t ws_size,
                              hipStream_t stream)
{
    const int*   inputs       = (const int*)d_in[0];
    const int*   sent_lengths = (const int*)d_in[1];
    const int*   sent_counts  = (const int*)d_in[2];
    const float* embed   = (const float*)d_in[3];
    const float* wWih_f  = (const float*)d_in[4];
    const float* wWhh_f  = (const float*)d_in[5];
    const float* wbih_f  = (const float*)d_in[6];
    const float* wbhh_f  = (const float*)d_in[7];
    const float* wWih_b  = (const float*)d_in[8];
    const float* wWhh_b  = (const float*)d_in[9];
    const float* wbih_b  = (const float*)d_in[10];
    const float* wbhh_b  = (const float*)d_in[11];
    const float* sWih_f  = (const float*)d_in[12];
    const float* sWhh_f  = (const float*)d_in[13];
    const float* sbih_f  = (const float*)d_in[14];
    const float* sbhh_f  = (const float*)d_in[15];
    const float* sWih_b  = (const float*)d_in[16];
    const float* sWhh_b  = (const float*)d_in[17];
    const float* sbih_b  = (const float*)d_in[18];
    const float* sbhh_b  = (const float*)d_in[19];
    const float* fc1_w   = (const float*)d_in[20];
    const float* fc1_b   = (const float*)d_in[21];
    const float* fc2_w   = (const float*)d_in[22];
    const float* fc2_b   = (const float*)d_in[23];

    float* ws = (float*)d_ws;
    const size_t projT_elems = (size_t)VOCAB * NPROJ;
    const size_t xgs_elems   = (size_t)NSENT * NPROJ;
    const size_t h_elems     = (size_t)NSENT * HDIM;
    const size_t hs_elems    = (size_t)NREV * HDIM;
    float* projT = ws;
    float* xgs   = projT + projT_elems;
    float* hf    = xgs + xgs_elems;
    float* hb    = hf + h_elems;
    float* hsf   = hb + h_elems;
    float* hsb   = hsf + hs_elems;
    int* order1 = (int*)(hsb + hs_elems);          // [NSENT]
    int* hist1  = order1 + NSENT;                  // [65]
    int* order2 = hist1 + 65;                      // [NREV]
    int* hist2  = order2 + NREV;                   // [65]

    size_t need = (projT_elems + xgs_elems + 2*h_elems + 2*hs_elems) * sizeof(float)
                + (NSENT + NREV + 130) * sizeof(int);
    if (ws_size < need) return;

    // 0) counting sort of both length arrays
    sort_init<<<1, 65, 0, stream>>>(hist1);
    sort_init<<<1, 65, 0, stream>>>(hist2);
    sort_hist<<<(NSENT + 255) / 256, 256, 0, stream>>>(sent_lengths, NSENT, hist1);
    sort_hist<<<(NREV + 255) / 256, 256, 0, stream>>>(sent_counts, NREV, hist2);
    sort_scan<<<1, 1, 0, stream>>>(hist1, WW);
    sort_scan<<<1, 1, 0, stream>>>(hist2, SS);
    sort_scatter<<<(NSENT + 255) / 256, 256, 0, stream>>>(sent_lengths, NSENT, hist1, order1);
    sort_scatter<<<(NREV + 255) / 256, 256, 0, stream>>>(sent_counts, NREV, hist2, order2);

    // 1) projected-embedding table
    {
        dim3 grid(NPROJ / TS, (VOCAB + TS - 1) / TS);   // 12 x 782
        gemm2_bias<<<grid, 256, 0, stream>>>(
            embed, nullptr, VOCAB, EDIM,
            wWih_f, wWih_b, wbih_f, wbih_b, projT);
    }
    // 2) word-level BiGRU last-h (MFMA scan, tiles of 16 sorted seqs)
    {
        int numTiles = NSENT / 16;                      // 200
        gru_mfma<true, WW><<<2 * numTiles, 512, 0, stream>>>(
            projT, inputs, sent_lengths, order1,
            wWhh_f, wWhh_b, wbhh_f, wbhh_b,
            hf, hb, NSENT, numTiles);
    }
    // 3) sentence-level input projections
    {
        dim3 grid(NPROJ / TS, NSENT / TS);              // 12 x 50
        gemm2_bias<<<grid, 256, 0, stream>>>(
            hf, hb, NSENT, HDIM,
            sWih_f, sWih_b, sbih_f, sbih_b, xgs);
    }
    // 4) sentence-level BiGRU last-h (same MFMA kernel)
    {
        int numTiles = NREV / 16;                       // 10
        gru_mfma<false, SS><<<2 * numTiles, 512, 0, stream>>>(
            xgs, nullptr, sent_counts, order2,
            sWhh_f, sWhh_b, sbhh_f, sbhh_b,
            hsf, hsb, NREV, numTiles);
    }
    // 5) FC head -> r_stars, then p_stars
    head_kernel<<<NREV, 64, 0, stream>>>(hsf, hsb, fc1_w, fc1_b, fc2_w, fc2_b,
                                         (float*)d_out);
    mean_kernel<<<1, 64, 0, stream>>>((float*)d_out);
}

// Round 6
// 428.119 us; speedup vs baseline: 3.4506x; 1.3828x over previous
//
#include <hip/hip_runtime.h>
#include <hip/hip_bf16.h>
#include <cstddef>

// ---------------------------------------------------------------------------
// Problem dims
// ---------------------------------------------------------------------------
#define VOCAB 50000
#define EDIM  200
#define HDIM  128
#define BB 16
#define RR 10
#define SS 20
#define WW 64
#define NSENT (BB*RR*SS)   // 3200 word-level sequences
#define NREV  (BB*RR)      // 160 sentence-level sequences
#define G3    (3*HDIM)     // 384 gate rows per direction
#define NPROJ (2*G3)       // 768

// ---------------------------------------------------------------------------
// bf16 helpers (RNE via bit trick)
// ---------------------------------------------------------------------------
static __device__ __forceinline__ short f2bf(float f) {
    union { float f; unsigned u; } v; v.f = f;
    unsigned r = v.u + 0x7FFFu + ((v.u >> 16) & 1u);
    return (short)(r >> 16);
}
static __device__ __forceinline__ float bf2f(short s) {
    union { unsigned u; float f; } v;
    v.u = ((unsigned)(unsigned short)s) << 16;
    return v.f;
}
static __device__ __forceinline__ float fsigmoid(float x) {
    return 1.f / (1.f + __expf(-x));
}
static __device__ __forceinline__ float ftanh(float x) {
    float xc = fminf(fmaxf(x, -15.f), 15.f);
    float e = __expf(-2.f * xc);
    return (1.f - e) / (1.f + e);
}

// ---------------------------------------------------------------------------
// Split-bf16 MFMA GEMM for the projection table:
//   C[M x 768] = A[M x 200] @ [B0;B1]^T + [bias0;bias1]
// Tile 128x128, 256 threads (4 waves, each a 64x64 quadrant).
// K padded 200 -> 224 (7 chunks of 32, zero-filled). Split-bf16:
// D = Ah*Bh + Ah*Bl + Al*Bh (err ~2^-17). Layouts per m91:
// A/B frag lane l: row/col=l&15, k=(l>>4)*8+j; C/D: col=lane&15,
// row=(lane>>4)*4+reg.
// ---------------------------------------------------------------------------
#define GM_LDK 40   // shorts per LDS row: 32 + 8 pad (80 B -> 2-way max)

__global__ __launch_bounds__(256, 2) void gemm_mfma_bias(
    const float* __restrict__ A, int M,
    const float* __restrict__ B0, const float* __restrict__ B1,
    const float* __restrict__ bias0, const float* __restrict__ bias1,
    float* __restrict__ C)
{
    using bf16x8 = __attribute__((ext_vector_type(8))) short;
    using f32x4  = __attribute__((ext_vector_type(4))) float;

    const int ct = blockIdx.x;            // 0..5  (128-col tiles over 768)
    const int rt = blockIdx.y;            // 128-row tiles over M
    const int tid = threadIdx.x;          // 0..255
    const int lane = tid & 63;
    const int wid  = tid >> 6;            // 0..3
    const int rlane = lane & 15;
    const int kgrp  = lane >> 4;          // 0..3

    const int rowBase = rt * 128;
    const int colBase = ct * 128;
    const float* Bsrc = (colBase < G3) ? B0 : B1;
    const int bcol = (colBase < G3) ? colBase : (colBase - G3);

    __shared__ short Ahi[128][GM_LDK], Alo[128][GM_LDK];
    __shared__ short Bhi[128][GM_LDK], Blo[128][GM_LDK];

    const int wrow = (wid >> 1) * 64;     // wave quadrant origin
    const int wcol = (wid & 1) * 64;

    f32x4 acc[4][4];
    #pragma unroll
    for (int i = 0; i < 4; ++i)
        #pragma unroll
        for (int j = 0; j < 4; ++j) acc[i][j] = {0.f, 0.f, 0.f, 0.f};

    const int srow = tid >> 1;            // staging row/col 0..127
    const int skh  = (tid & 1) << 4;      // 0 or 16

    for (int k0 = 0; k0 < 224; k0 += 32) {
        // ---- stage A chunk (f32 -> split-bf16) ----
        {
            const int grow = rowBase + srow;
            float v[16];
            #pragma unroll
            for (int i = 0; i < 4; ++i) {
                const int k = k0 + skh + i * 4;
                float4 x = {0.f, 0.f, 0.f, 0.f};
                if (grow < M && k + 3 < EDIM)
                    x = *(const float4*)&A[(size_t)grow * EDIM + k];
                v[4*i+0] = x.x; v[4*i+1] = x.y; v[4*i+2] = x.z; v[4*i+3] = x.w;
            }
            bf16x8 h0, h1, l0, l1;
            #pragma unroll
            for (int i = 0; i < 8; ++i) {
                short a = f2bf(v[i]);
                h0[i] = a; l0[i] = f2bf(v[i] - bf2f(a));
                short b = f2bf(v[i + 8]);
                h1[i] = b; l1[i] = f2bf(v[i + 8] - bf2f(b));
            }
            *(bf16x8*)&Ahi[srow][skh]     = h0;
            *(bf16x8*)&Ahi[srow][skh + 8] = h1;
            *(bf16x8*)&Alo[srow][skh]     = l0;
            *(bf16x8*)&Alo[srow][skh + 8] = l1;
        }
        // ---- stage B chunk ----
        {
            const int gcol = bcol + srow;          // < 384 always
            float v[16];
            #pragma unroll
            for (int i = 0; i < 4; ++i) {
                const int k = k0 + skh + i * 4;
                float4 x = {0.f, 0.f, 0.f, 0.f};
                if (k + 3 < EDIM)
                    x = *(const float4*)&Bsrc[(size_t)gcol * EDIM + k];
                v[4*i+0] = x.x; v[4*i+1] = x.y; v[4*i+2] = x.z; v[4*i+3] = x.w;
            }
            bf16x8 h0, h1, l0, l1;
            #pragma unroll
            for (int i = 0; i < 8; ++i) {
                short a = f2bf(v[i]);
                h0[i] = a; l0[i] = f2bf(v[i] - bf2f(a));
                short b = f2bf(v[i + 8]);
                h1[i] = b; l1[i] = f2bf(v[i + 8] - bf2f(b));
            }
            *(bf16x8*)&Bhi[srow][skh]     = h0;
            *(bf16x8*)&Bhi[srow][skh + 8] = h1;
            *(bf16x8*)&Blo[srow][skh]     = l0;
            *(bf16x8*)&Blo[srow][skh + 8] = l1;
        }
        __syncthreads();
        // ---- fragments + MFMA ----
        bf16x8 ah[4], al[4], bh[4], bl[4];
        #pragma unroll
        for (int mr = 0; mr < 4; ++mr) {
            ah[mr] = *(const bf16x8*)&Ahi[wrow + mr * 16 + rlane][kgrp * 8];
            al[mr] = *(const bf16x8*)&Alo[wrow + mr * 16 + rlane][kgrp * 8];
        }
        #pragma unroll
        for (int nc = 0; nc < 4; ++nc) {
            bh[nc] = *(const bf16x8*)&Bhi[wcol + nc * 16 + rlane][kgrp * 8];
            bl[nc] = *(const bf16x8*)&Blo[wcol + nc * 16 + rlane][kgrp * 8];
        }
        #pragma unroll
        for (int mr = 0; mr < 4; ++mr)
            #pragma unroll
            for (int nc = 0; nc < 4; ++nc) {
                acc[mr][nc] = __builtin_amdgcn_mfma_f32_16x16x32_bf16(
                    ah[mr], bh[nc], acc[mr][nc], 0, 0, 0);
                acc[mr][nc] = __builtin_amdgcn_mfma_f32_16x16x32_bf16(
                    ah[mr], bl[nc], acc[mr][nc], 0, 0, 0);
                acc[mr][nc] = __builtin_amdgcn_mfma_f32_16x16x32_bf16(
                    al[mr], bh[nc], acc[mr][nc], 0, 0, 0);
            }
        __syncthreads();
    }

    // ---- epilogue: bias + store ----
    const float* bs = (colBase < G3) ? bias0 : bias1;
    #pragma unroll
    for (int nc = 0; nc < 4; ++nc) {
        const int c = wcol + nc * 16 + rlane;
        const float bv = bs[bcol + c];
        #pragma unroll
        for (int mr = 0; mr < 4; ++mr) {
            #pragma unroll
            for (int r = 0; r < 4; ++r) {
                const int grow = rowBase + wrow + mr * 16 + kgrp * 4 + r;
                if (grow < M)
                    C[(size_t)grow * NPROJ + colBase + c] = acc[mr][nc][r] + bv;
            }
        }
    }
}

// ---------------------------------------------------------------------------
// Small f32 GEMM (kept for the 3200x128x768 sentence-input projection):
//   C[M x 768] = (0.5*(A0+A1))[M x K] @ [B0;B1]^T + [bias0;bias1]
// ---------------------------------------------------------------------------
#define TS 64
#define KC 32

__global__ __launch_bounds__(256) void gemm2_bias(
    const float* __restrict__ A0, const float* __restrict__ A1,
    int M, int K,
    const float* __restrict__ B0, const float* __restrict__ B1,
    const float* __restrict__ bias0, const float* __restrict__ bias1,
    float* __restrict__ C)
{
    __shared__ __align__(16) float At[KC][TS + 4];
    __shared__ __align__(16) float Bt[KC][TS + 4];

    const int ct = blockIdx.x;
    const int rt = blockIdx.y;
    const int tid = threadIdx.x;
    const int r0 = (tid >> 4) << 2;
    const int c0 = (tid & 15) << 2;
    const int rowBase = rt * TS;
    const int colBase = ct * TS;

    const float* Bsrc = (colBase < G3) ? B0 : B1;
    const int bcolBase = (colBase < G3) ? colBase : (colBase - G3);

    float acc[4][4];
    #pragma unroll
    for (int i = 0; i < 4; ++i)
        #pragma unroll
        for (int j = 0; j < 4; ++j) acc[i][j] = 0.f;

    for (int k0 = 0; k0 < K; k0 += KC) {
        const int kc = min(KC, K - k0);
        for (int f = tid; f < TS * KC; f += 256) {
            int r = f >> 5;
            int k = f & 31;
            float v = 0.f;
            int row = rowBase + r;
            if (k < kc && row < M) {
                size_t idx = (size_t)row * K + k0 + k;
                v = A0[idx];
                if (A1) v = 0.5f * (v + A1[idx]);
            }
            At[k][r] = v;
        }
        for (int f = tid; f < TS * KC; f += 256) {
            int r = f >> 5;
            int k = f & 31;
            float v = 0.f;
            if (k < kc) v = Bsrc[(size_t)(bcolBase + r) * K + k0 + k];
            Bt[k][r] = v;
        }
        __syncthreads();
        #pragma unroll 8
        for (int k = 0; k < kc; ++k) {
            float4 av = *(const float4*)&At[k][r0];
            float4 bv = *(const float4*)&Bt[k][c0];
            acc[0][0] = fmaf(av.x, bv.x, acc[0][0]);
            acc[0][1] = fmaf(av.x, bv.y, acc[0][1]);
            acc[0][2] = fmaf(av.x, bv.z, acc[0][2]);
            acc[0][3] = fmaf(av.x, bv.w, acc[0][3]);
            acc[1][0] = fmaf(av.y, bv.x, acc[1][0]);
            acc[1][1] = fmaf(av.y, bv.y, acc[1][1]);
            acc[1][2] = fmaf(av.y, bv.z, acc[1][2]);
            acc[1][3] = fmaf(av.y, bv.w, acc[1][3]);
            acc[2][0] = fmaf(av.z, bv.x, acc[2][0]);
            acc[2][1] = fmaf(av.z, bv.y, acc[2][1]);
            acc[2][2] = fmaf(av.z, bv.z, acc[2][2]);
            acc[2][3] = fmaf(av.z, bv.w, acc[2][3]);
            acc[3][0] = fmaf(av.w, bv.x, acc[3][0]);
            acc[3][1] = fmaf(av.w, bv.y, acc[3][1]);
            acc[3][2] = fmaf(av.w, bv.z, acc[3][2]);
            acc[3][3] = fmaf(av.w, bv.w, acc[3][3]);
        }
        __syncthreads();
    }

    const float* bsrc = (colBase < G3) ? bias0 : bias1;
    #pragma unroll
    for (int i = 0; i < 4; ++i) {
        int row = rowBase + r0 + i;
        if (row < M) {
            float* cp = C + (size_t)row * NPROJ + colBase + c0;
            #pragma unroll
            for (int j = 0; j < 4; ++j)
                cp[j] = acc[i][j] + bsrc[bcolBase + c0 + j];
        }
    }
}

// ---------------------------------------------------------------------------
// Counting sort by length (order within bucket race-dependent; results are
// written per-sequence so final output is deterministic).
// ---------------------------------------------------------------------------
__global__ void sort_init(int* hist) {
    if (threadIdx.x < 65) hist[threadIdx.x] = 0;
}
__global__ void sort_hist(const int* __restrict__ lengths, int n, int* hist) {
    int i = blockIdx.x * 256 + threadIdx.x;
    if (i < n) atomicAdd(&hist[lengths[i]], 1);
}
__global__ void sort_scan(int* hist, int maxlen) {
    if (threadIdx.x == 0) {
        int acc = 0;
        for (int l = 1; l <= maxlen; ++l) { int c = hist[l]; hist[l] = acc; acc += c; }
    }
}
__global__ void sort_scatter(const int* __restrict__ lengths, int n,
                             int* hist, int* order) {
    int i = blockIdx.x * 256 + threadIdx.x;
    if (i < n) {
        int pos = atomicAdd(&hist[lengths[i]], 1);
        order[pos] = i;
    }
}

// ---------------------------------------------------------------------------
// MFMA GRU scan (unchanged from round 5).
// ---------------------------------------------------------------------------
template<bool WORD, int TMAX>
__global__ __launch_bounds__(512, 2) void gru_mfma(
    const float* __restrict__ table,
    const int*   __restrict__ tokens,
    const int*   __restrict__ lengths,
    const int*   __restrict__ order,
    const float* __restrict__ Whh_f, const float* __restrict__ Whh_b,
    const float* __restrict__ bhh_f, const float* __restrict__ bhh_b,
    float* __restrict__ hout_f, float* __restrict__ hout_b,
    int numSeq, int numTiles)
{
    using bf16x8 = __attribute__((ext_vector_type(8))) short;
    using f32x4  = __attribute__((ext_vector_type(4))) float;

    const int dir  = (blockIdx.x >= numTiles) ? 1 : 0;
    const int rawt = dir ? (blockIdx.x - numTiles) : blockIdx.x;
    const int tile = numTiles - 1 - rawt;      // longest tiles first
    const int base = tile * 16;
    const int tid  = threadIdx.x;              // 0..511
    const int lane = tid & 63;
    const int wid  = tid >> 6;                 // 0..7
    const int rlane = lane & 15;
    const int kgrp  = lane >> 4;               // 0..3

    __shared__ __align__(16) float sh_h[16][132];
    __shared__ float sh_hg[16][388];
    __shared__ int sh_len[16];
    __shared__ int sh_ord[16];
    __shared__ int sh_tok[WORD ? 16 * WW : 1];
    __shared__ int sh_maxlen;

    const float* Whh = dir ? Whh_b : Whh_f;
    const float* bhh = dir ? bhh_b : bhh_f;
    bf16x8 Bhi[3][4], Blo[3][4];
    float bb[3];
    #pragma unroll
    for (int nt = 0; nt < 3; ++nt) {
        const int cb = (3 * wid + nt) * 16;
        const float* wrow = Whh + (size_t)(cb + rlane) * HDIM;
        bb[nt] = bhh[cb + rlane];
        #pragma unroll
        for (int kc = 0; kc < 4; ++kc) {
            const float* wp = wrow + kc * 32 + kgrp * 8;
            float4 w0 = *(const float4*)wp;
            float4 w1 = *(const float4*)(wp + 4);
            float wv[8] = {w0.x, w0.y, w0.z, w0.w, w1.x, w1.y, w1.z, w1.w};
            #pragma unroll
            for (int j = 0; j < 8; ++j) {
                short hi = f2bf(wv[j]);
                Bhi[nt][kc][j] = hi;
                Blo[nt][kc][j] = f2bf(wv[j] - bf2f(hi));
            }
        }
    }

    if (tid < 16) {
        int pos = base + tid;
        int seq = (pos < numSeq) ? order[pos] : -1;
        sh_ord[tid] = seq;
        sh_len[tid] = (seq >= 0) ? lengths[seq] : 0;
    }
    __syncthreads();
    if (WORD) {
        for (int f = tid; f < 16 * WW; f += 512) {
            int s = f >> 6;
            int seq = sh_ord[s];
            sh_tok[f] = (seq >= 0) ? tokens[(size_t)seq * WW + (f & 63)] : 0;
        }
    }
    for (int u = tid; u < 16 * HDIM; u += 512)
        sh_h[u >> 7][u & 127] = 0.f;
    if (tid == 0) {
        int m = 0;
        for (int s = 0; s < 16; ++s) m = max(m, sh_len[s]);
        sh_maxlen = m;
    }
    const int s0 = tid >> 7;          // 0..3
    const int e  = tid & 127;
    int glen[4], gord[4];
    #pragma unroll
    for (int j = 0; j < 4; ++j) {
        glen[j] = sh_len[s0 + 4 * j];
        gord[j] = sh_ord[s0 + 4 * j];
    }
    __syncthreads();
    const int maxlen = sh_maxlen;

    auto fetch_xg = [&](int t, float* fr, float* fz, float* fn) {
        #pragma unroll
        for (int j = 0; j < 4; ++j) {
            fr[j] = 0.f; fz[j] = 0.f; fn[j] = 0.f;
            if (t < glen[j]) {
                int tt = dir ? (glen[j] - 1 - t) : t;
                size_t row;
                if (WORD) row = (size_t)sh_tok[(s0 + 4 * j) * WW + tt];
                else      row = (size_t)gord[j] * TMAX + tt;
                const float* xg = table + row * NPROJ + dir * G3 + e;
                fr[j] = xg[0]; fz[j] = xg[HDIM]; fn[j] = xg[2 * HDIM];
            }
        }
    };

    float pr[4], pz[4], pn[4];
    fetch_xg(0, pr, pz, pn);

    for (int t = 0; t < maxlen; ++t) {
        bf16x8 Ahi[4], Alo[4];
        #pragma unroll
        for (int kc = 0; kc < 4; ++kc) {
            const float* hp = &sh_h[rlane][kc * 32 + kgrp * 8];
            float4 h0 = *(const float4*)hp;
            float4 h1 = *(const float4*)(hp + 4);
            float hv[8] = {h0.x, h0.y, h0.z, h0.w, h1.x, h1.y, h1.z, h1.w};
            #pragma unroll
            for (int j = 0; j < 8; ++j) {
                short hi = f2bf(hv[j]);
                Ahi[kc][j] = hi;
                Alo[kc][j] = f2bf(hv[j] - bf2f(hi));
            }
        }
        f32x4 acc[3];
        #pragma unroll
        for (int nt = 0; nt < 3; ++nt) {
            acc[nt] = {0.f, 0.f, 0.f, 0.f};
            #pragma unroll
            for (int kc = 0; kc < 4; ++kc)
                acc[nt] = __builtin_amdgcn_mfma_f32_16x16x32_bf16(
                    Ahi[kc], Bhi[nt][kc], acc[nt], 0, 0, 0);
            #pragma unroll
            for (int kc = 0; kc < 4; ++kc)
                acc[nt] = __builtin_amdgcn_mfma_f32_16x16x32_bf16(
                    Ahi[kc], Blo[nt][kc], acc[nt], 0, 0, 0);
            #pragma unroll
            for (int kc = 0; kc < 4; ++kc)
                acc[nt] = __builtin_amdgcn_mfma_f32_16x16x32_bf16(
                    Alo[kc], Bhi[nt][kc], acc[nt], 0, 0, 0);
        }
        #pragma unroll
        for (int nt = 0; nt < 3; ++nt) {
            const int cb = (3 * wid + nt) * 16;
            #pragma unroll
            for (int r = 0; r < 4; ++r)
                sh_hg[kgrp * 4 + r][cb + rlane] = acc[nt][r] + bb[nt];
        }
        float qr[4], qz[4], qn[4];
        fetch_xg(t + 1, qr, qz, qn);
        __syncthreads();
        #pragma unroll
        for (int j = 0; j < 4; ++j) {
            if (t < glen[j]) {
                int s = s0 + 4 * j;
                float hgr = sh_hg[s][e];
                float hgz = sh_hg[s][e + HDIM];
                float hgn = sh_hg[s][e + 2 * HDIM];
                float hold = sh_h[s][e];
                float rg = fsigmoid(pr[j] + hgr);
                float zg = fsigmoid(pz[j] + hgz);
                float ng = ftanh(pn[j] + rg * hgn);
                sh_h[s][e] = (1.f - zg) * ng + zg * hold;
            }
        }
        __syncthreads();
        #pragma unroll
        for (int j = 0; j < 4; ++j) { pr[j] = qr[j]; pz[j] = qz[j]; pn[j] = qn[j]; }
    }

    float* hout = dir ? hout_b : hout_f;
    for (int u = tid; u < 16 * HDIM; u += 512) {
        int s = u >> 7, ee = u & 127;
        int seq = sh_ord[s];
        if (seq >= 0) hout[(size_t)seq * HDIM + ee] = sh_h[s][ee];
    }
}

// ---------------------------------------------------------------------------
// Head + mean
// ---------------------------------------------------------------------------
__global__ __launch_bounds__(64) void head_kernel(
    const float* __restrict__ hsf, const float* __restrict__ hsb,
    const float* __restrict__ fc1_w, const float* __restrict__ fc1_b,
    const float* __restrict__ fc2_w, const float* __restrict__ fc2_b,
    float* __restrict__ out)
{
    const int br = blockIdx.x;
    const int j = threadIdx.x;
    __shared__ float rev[HDIM];
    for (int ee = j; ee < HDIM; ee += 64)
        rev[ee] = 0.5f * (hsf[(size_t)br * HDIM + ee] + hsb[(size_t)br * HDIM + ee]);
    __syncthreads();
    float acc = 0.f;
    #pragma unroll
    for (int k = 0; k < HDIM; ++k)
        acc = fmaf(fc1_w[(size_t)j * HDIM + k], rev[k], acc);
    acc += fc1_b[j];
    const float alpha = 1.6732632423543772f;
    const float scale = 1.0507009873554805f;
    float h1 = scale * (acc > 0.f ? acc : alpha * (expf(acc) - 1.f));
    float contrib = h1 * fc2_w[j];
    #pragma unroll
    for (int off = 32; off > 0; off >>= 1)
        contrib += __shfl_down(contrib, off);
    if (j == 0) out[16 + br] = contrib + fc2_b[0];
}

__global__ void mean_kernel(float* __restrict__ out)
{
    int b = threadIdx.x;
    if (b < BB) {
        float s = 0.f;
        for (int r = 0; r < RR; ++r) s += out[16 + b * RR + r];
        out[b] = s / (float)RR;
    }
}

// ---------------------------------------------------------------------------
// Launch
// ---------------------------------------------------------------------------
extern "C" void kernel_launch(void* const* d_in, const int* in_sizes, int n_in,
                              void* d_out, int out_size, void* d_ws, size_t ws_size,
                              hipStream_t stream)
{
    const int*   inputs       = (const int*)d_in[0];
    const int*   sent_lengths = (const int*)d_in[1];
    const int*   sent_counts  = (const int*)d_in[2];
    const float* embed   = (const float*)d_in[3];
    const float* wWih_f  = (const float*)d_in[4];
    const float* wWhh_f  = (const float*)d_in[5];
    const float* wbih_f  = (const float*)d_in[6];
    const float* wbhh_f  = (const float*)d_in[7];
    const float* wWih_b  = (const float*)d_in[8];
    const float* wWhh_b  = (const float*)d_in[9];
    const float* wbih_b  = (const float*)d_in[10];
    const float* wbhh_b  = (const float*)d_in[11];
    const float* sWih_f  = (const float*)d_in[12];
    const float* sWhh_f  = (const float*)d_in[13];
    const float* sbih_f  = (const float*)d_in[14];
    const float* sbhh_f  = (const float*)d_in[15];
    const float* sWih_b  = (const float*)d_in[16];
    const float* sWhh_b  = (const float*)d_in[17];
    const float* sbih_b  = (const float*)d_in[18];
    const float* sbhh_b  = (const float*)d_in[19];
    const float* fc1_w   = (const float*)d_in[20];
    const float* fc1_b   = (const float*)d_in[21];
    const float* fc2_w   = (const float*)d_in[22];
    const float* fc2_b   = (const float*)d_in[23];

    float* ws = (float*)d_ws;
    const size_t projT_elems = (size_t)VOCAB * NPROJ;
    const size_t xgs_elems   = (size_t)NSENT * NPROJ;
    const size_t h_elems     = (size_t)NSENT * HDIM;
    const size_t hs_elems    = (size_t)NREV * HDIM;
    float* projT = ws;
    float* xgs   = projT + projT_elems;
    float* hf    = xgs + xgs_elems;
    float* hb    = hf + h_elems;
    float* hsf   = hb + h_elems;
    float* hsb   = hsf + hs_elems;
    int* order1 = (int*)(hsb + hs_elems);          // [NSENT]
    int* hist1  = order1 + NSENT;                  // [65]
    int* order2 = hist1 + 65;                      // [NREV]
    int* hist2  = order2 + NREV;                   // [65]

    size_t need = (projT_elems + xgs_elems + 2*h_elems + 2*hs_elems) * sizeof(float)
                + (NSENT + NREV + 130) * sizeof(int);
    if (ws_size < need) return;

    // 0) counting sort of both length arrays
    sort_init<<<1, 65, 0, stream>>>(hist1);
    sort_init<<<1, 65, 0, stream>>>(hist2);
    sort_hist<<<(NSENT + 255) / 256, 256, 0, stream>>>(sent_lengths, NSENT, hist1);
    sort_hist<<<(NREV + 255) / 256, 256, 0, stream>>>(sent_counts, NREV, hist2);
    sort_scan<<<1, 1, 0, stream>>>(hist1, WW);
    sort_scan<<<1, 1, 0, stream>>>(hist2, SS);
    sort_scatter<<<(NSENT + 255) / 256, 256, 0, stream>>>(sent_lengths, NSENT, hist1, order1);
    sort_scatter<<<(NREV + 255) / 256, 256, 0, stream>>>(sent_counts, NREV, hist2, order2);

    // 1) projected-embedding table via split-bf16 MFMA
    {
        dim3 grid(NPROJ / 128, (VOCAB + 127) / 128);    // 6 x 391
        gemm_mfma_bias<<<grid, 256, 0, stream>>>(
            embed, VOCAB,
            wWih_f, wWih_b, wbih_f, wbih_b, projT);
    }
    // 2) word-level BiGRU last-h (MFMA scan, tiles of 16 sorted seqs)
    {
        int numTiles = NSENT / 16;                      // 200
        gru_mfma<true, WW><<<2 * numTiles, 512, 0, stream>>>(
            projT, inputs, sent_lengths, order1,
            wWhh_f, wWhh_b, wbhh_f, wbhh_b,
            hf, hb, NSENT, numTiles);
    }
    // 3) sentence-level input projections (small, stays f32)
    {
        dim3 grid(NPROJ / TS, NSENT / TS);              // 12 x 50
        gemm2_bias<<<grid, 256, 0, stream>>>(
            hf, hb, NSENT, HDIM,
            sWih_f, sWih_b, sbih_f, sbih_b, xgs);
    }
    // 4) sentence-level BiGRU last-h (MFMA scan)
    {
        int numTiles = NREV / 16;                       // 10
        gru_mfma<false, SS><<<2 * numTiles, 512, 0, stream>>>(
            xgs, nullptr, sent_counts, order2,
            sWhh_f, sWhh_b, sbhh_f, sbhh_b,
            hsf, hsb, NREV, numTiles);
    }
    // 5) FC head -> r_stars, then p_stars
    head_kernel<<<NREV, 64, 0, stream>>>(hsf, hsb, fc1_w, fc1_b, fc2_w, fc2_b,
                                         (float*)d_out);
    mean_kernel<<<1, 64, 0, stream>>>((float*)d_out);
}

// Round 7
// 362.078 us; speedup vs baseline: 4.0800x; 1.1824x over previous
//
#include <hip/hip_runtime.h>
#include <hip/hip_bf16.h>
#include <cstddef>

// ---------------------------------------------------------------------------
// Problem dims
// ---------------------------------------------------------------------------
#define VOCAB 50000
#define EDIM  200
#define HDIM  128
#define BB 16
#define RR 10
#define SS 20
#define WW 64
#define NSENT (BB*RR*SS)   // 3200 word-level sequences
#define NREV  (BB*RR)      // 160 sentence-level sequences
#define G3    (3*HDIM)     // 384 gate rows per direction
#define NPROJ (2*G3)       // 768

// ---------------------------------------------------------------------------
// bf16 helpers (RNE via bit trick)
// ---------------------------------------------------------------------------
static __device__ __forceinline__ short f2bf(float f) {
    union { float f; unsigned u; } v; v.f = f;
    unsigned r = v.u + 0x7FFFu + ((v.u >> 16) & 1u);
    return (short)(r >> 16);
}
static __device__ __forceinline__ float bf2f(short s) {
    union { unsigned u; float f; } v;
    v.u = ((unsigned)(unsigned short)s) << 16;
    return v.f;
}
static __device__ __forceinline__ float fsigmoid(float x) {
    return 1.f / (1.f + __expf(-x));
}
static __device__ __forceinline__ float ftanh(float x) {
    float xc = fminf(fmaxf(x, -15.f), 15.f);
    float e = __expf(-2.f * xc);
    return (1.f - e) / (1.f + e);
}

// ---------------------------------------------------------------------------
// Split-bf16 MFMA GEMM for the projection table (unchanged from round 6):
//   C[M x 768] = A[M x 200] @ [B0;B1]^T + [bias0;bias1]
// ---------------------------------------------------------------------------
#define GM_LDK 40   // shorts per LDS row: 32 + 8 pad

__global__ __launch_bounds__(256, 2) void gemm_mfma_bias(
    const float* __restrict__ A, int M,
    const float* __restrict__ B0, const float* __restrict__ B1,
    const float* __restrict__ bias0, const float* __restrict__ bias1,
    float* __restrict__ C)
{
    using bf16x8 = __attribute__((ext_vector_type(8))) short;
    using f32x4  = __attribute__((ext_vector_type(4))) float;

    const int ct = blockIdx.x;
    const int rt = blockIdx.y;
    const int tid = threadIdx.x;
    const int lane = tid & 63;
    const int wid  = tid >> 6;
    const int rlane = lane & 15;
    const int kgrp  = lane >> 4;

    const int rowBase = rt * 128;
    const int colBase = ct * 128;
    const float* Bsrc = (colBase < G3) ? B0 : B1;
    const int bcol = (colBase < G3) ? colBase : (colBase - G3);

    __shared__ short Ahi[128][GM_LDK], Alo[128][GM_LDK];
    __shared__ short Bhi[128][GM_LDK], Blo[128][GM_LDK];

    const int wrow = (wid >> 1) * 64;
    const int wcol = (wid & 1) * 64;

    f32x4 acc[4][4];
    #pragma unroll
    for (int i = 0; i < 4; ++i)
        #pragma unroll
        for (int j = 0; j < 4; ++j) acc[i][j] = {0.f, 0.f, 0.f, 0.f};

    const int srow = tid >> 1;
    const int skh  = (tid & 1) << 4;

    for (int k0 = 0; k0 < 224; k0 += 32) {
        {
            const int grow = rowBase + srow;
            float v[16];
            #pragma unroll
            for (int i = 0; i < 4; ++i) {
                const int k = k0 + skh + i * 4;
                float4 x = {0.f, 0.f, 0.f, 0.f};
                if (grow < M && k + 3 < EDIM)
                    x = *(const float4*)&A[(size_t)grow * EDIM + k];
                v[4*i+0] = x.x; v[4*i+1] = x.y; v[4*i+2] = x.z; v[4*i+3] = x.w;
            }
            bf16x8 h0, h1, l0, l1;
            #pragma unroll
            for (int i = 0; i < 8; ++i) {
                short a = f2bf(v[i]);
                h0[i] = a; l0[i] = f2bf(v[i] - bf2f(a));
                short b = f2bf(v[i + 8]);
                h1[i] = b; l1[i] = f2bf(v[i + 8] - bf2f(b));
            }
            *(bf16x8*)&Ahi[srow][skh]     = h0;
            *(bf16x8*)&Ahi[srow][skh + 8] = h1;
            *(bf16x8*)&Alo[srow][skh]     = l0;
            *(bf16x8*)&Alo[srow][skh + 8] = l1;
        }
        {
            const int gcol = bcol + srow;
            float v[16];
            #pragma unroll
            for (int i = 0; i < 4; ++i) {
                const int k = k0 + skh + i * 4;
                float4 x = {0.f, 0.f, 0.f, 0.f};
                if (k + 3 < EDIM)
                    x = *(const float4*)&Bsrc[(size_t)gcol * EDIM + k];
                v[4*i+0] = x.x; v[4*i+1] = x.y; v[4*i+2] = x.z; v[4*i+3] = x.w;
            }
            bf16x8 h0, h1, l0, l1;
            #pragma unroll
            for (int i = 0; i < 8; ++i) {
                short a = f2bf(v[i]);
                h0[i] = a; l0[i] = f2bf(v[i] - bf2f(a));
                short b = f2bf(v[i + 8]);
                h1[i] = b; l1[i] = f2bf(v[i + 8] - bf2f(b));
            }
            *(bf16x8*)&Bhi[srow][skh]     = h0;
            *(bf16x8*)&Bhi[srow][skh + 8] = h1;
            *(bf16x8*)&Blo[srow][skh]     = l0;
            *(bf16x8*)&Blo[srow][skh + 8] = l1;
        }
        __syncthreads();
        bf16x8 ah[4], al[4], bh[4], bl[4];
        #pragma unroll
        for (int mr = 0; mr < 4; ++mr) {
            ah[mr] = *(const bf16x8*)&Ahi[wrow + mr * 16 + rlane][kgrp * 8];
            al[mr] = *(const bf16x8*)&Alo[wrow + mr * 16 + rlane][kgrp * 8];
        }
        #pragma unroll
        for (int nc = 0; nc < 4; ++nc) {
            bh[nc] = *(const bf16x8*)&Bhi[wcol + nc * 16 + rlane][kgrp * 8];
            bl[nc] = *(const bf16x8*)&Blo[wcol + nc * 16 + rlane][kgrp * 8];
        }
        #pragma unroll
        for (int mr = 0; mr < 4; ++mr)
            #pragma unroll
            for (int nc = 0; nc < 4; ++nc) {
                acc[mr][nc] = __builtin_amdgcn_mfma_f32_16x16x32_bf16(
                    ah[mr], bh[nc], acc[mr][nc], 0, 0, 0);
                acc[mr][nc] = __builtin_amdgcn_mfma_f32_16x16x32_bf16(
                    ah[mr], bl[nc], acc[mr][nc], 0, 0, 0);
                acc[mr][nc] = __builtin_amdgcn_mfma_f32_16x16x32_bf16(
                    al[mr], bh[nc], acc[mr][nc], 0, 0, 0);
            }
        __syncthreads();
    }

    const float* bs = (colBase < G3) ? bias0 : bias1;
    #pragma unroll
    for (int nc = 0; nc < 4; ++nc) {
        const int c = wcol + nc * 16 + rlane;
        const float bv = bs[bcol + c];
        #pragma unroll
        for (int mr = 0; mr < 4; ++mr) {
            #pragma unroll
            for (int r = 0; r < 4; ++r) {
                const int grow = rowBase + wrow + mr * 16 + kgrp * 4 + r;
                if (grow < M)
                    C[(size_t)grow * NPROJ + colBase + c] = acc[mr][nc][r] + bv;
            }
        }
    }
}

// ---------------------------------------------------------------------------
// Small f32 GEMM (sentence-input projection, 3200x128 @ ->768)
// ---------------------------------------------------------------------------
#define TS 64
#define KC 32

__global__ __launch_bounds__(256) void gemm2_bias(
    const float* __restrict__ A0, const float* __restrict__ A1,
    int M, int K,
    const float* __restrict__ B0, const float* __restrict__ B1,
    const float* __restrict__ bias0, const float* __restrict__ bias1,
    float* __restrict__ C)
{
    __shared__ __align__(16) float At[KC][TS + 4];
    __shared__ __align__(16) float Bt[KC][TS + 4];

    const int ct = blockIdx.x;
    const int rt = blockIdx.y;
    const int tid = threadIdx.x;
    const int r0 = (tid >> 4) << 2;
    const int c0 = (tid & 15) << 2;
    const int rowBase = rt * TS;
    const int colBase = ct * TS;

    const float* Bsrc = (colBase < G3) ? B0 : B1;
    const int bcolBase = (colBase < G3) ? colBase : (colBase - G3);

    float acc[4][4];
    #pragma unroll
    for (int i = 0; i < 4; ++i)
        #pragma unroll
        for (int j = 0; j < 4; ++j) acc[i][j] = 0.f;

    for (int k0 = 0; k0 < K; k0 += KC) {
        const int kc = min(KC, K - k0);
        for (int f = tid; f < TS * KC; f += 256) {
            int r = f >> 5;
            int k = f & 31;
            float v = 0.f;
            int row = rowBase + r;
            if (k < kc && row < M) {
                size_t idx = (size_t)row * K + k0 + k;
                v = A0[idx];
                if (A1) v = 0.5f * (v + A1[idx]);
            }
            At[k][r] = v;
        }
        for (int f = tid; f < TS * KC; f += 256) {
            int r = f >> 5;
            int k = f & 31;
            float v = 0.f;
            if (k < kc) v = Bsrc[(size_t)(bcolBase + r) * K + k0 + k];
            Bt[k][r] = v;
        }
        __syncthreads();
        #pragma unroll 8
        for (int k = 0; k < kc; ++k) {
            float4 av = *(const float4*)&At[k][r0];
            float4 bv = *(const float4*)&Bt[k][c0];
            acc[0][0] = fmaf(av.x, bv.x, acc[0][0]);
            acc[0][1] = fmaf(av.x, bv.y, acc[0][1]);
            acc[0][2] = fmaf(av.x, bv.z, acc[0][2]);
            acc[0][3] = fmaf(av.x, bv.w, acc[0][3]);
            acc[1][0] = fmaf(av.y, bv.x, acc[1][0]);
            acc[1][1] = fmaf(av.y, bv.y, acc[1][1]);
            acc[1][2] = fmaf(av.y, bv.z, acc[1][2]);
            acc[1][3] = fmaf(av.y, bv.w, acc[1][3]);
            acc[2][0] = fmaf(av.z, bv.x, acc[2][0]);
            acc[2][1] = fmaf(av.z, bv.y, acc[2][1]);
            acc[2][2] = fmaf(av.z, bv.z, acc[2][2]);
            acc[2][3] = fmaf(av.z, bv.w, acc[2][3]);
            acc[3][0] = fmaf(av.w, bv.x, acc[3][0]);
            acc[3][1] = fmaf(av.w, bv.y, acc[3][1]);
            acc[3][2] = fmaf(av.w, bv.z, acc[3][2]);
            acc[3][3] = fmaf(av.w, bv.w, acc[3][3]);
        }
        __syncthreads();
    }

    const float* bsrc = (colBase < G3) ? bias0 : bias1;
    #pragma unroll
    for (int i = 0; i < 4; ++i) {
        int row = rowBase + r0 + i;
        if (row < M) {
            float* cp = C + (size_t)row * NPROJ + colBase + c0;
            #pragma unroll
            for (int j = 0; j < 4; ++j)
                cp[j] = acc[i][j] + bsrc[bcolBase + c0 + j];
        }
    }
}

// ---------------------------------------------------------------------------
// Counting sort by length
// ---------------------------------------------------------------------------
__global__ void sort_init(int* hist) {
    if (threadIdx.x < 65) hist[threadIdx.x] = 0;
}
__global__ void sort_hist(const int* __restrict__ lengths, int n, int* hist) {
    int i = blockIdx.x * 256 + threadIdx.x;
    if (i < n) atomicAdd(&hist[lengths[i]], 1);
}
__global__ void sort_scan(int* hist, int maxlen) {
    if (threadIdx.x == 0) {
        int acc = 0;
        for (int l = 1; l <= maxlen; ++l) { int c = hist[l]; hist[l] = acc; acc += c; }
    }
}
__global__ void sort_scatter(const int* __restrict__ lengths, int n,
                             int* hist, int* order) {
    int i = blockIdx.x * 256 + threadIdx.x;
    if (i < n) {
        int pos = atomicAdd(&hist[lengths[i]], 1);
        order[pos] = i;
    }
}

// ---------------------------------------------------------------------------
// MFMA GRU scan, fused-gate mapping.
// One block = (tile of 16 sorted seqs, direction); 512 threads = 8 waves.
// Wave w owns gate cols {w*16 (r), 128+w*16 (z), 256+w*16 (n)} -> each lane
// holds hg_r/z/n for (seq=4*kgrp+j, e=w*16+rlane) in acc regs; gate update is
// fully in-register; h state (hold[4]) lives in regs. h is published to LDS
// only as pre-split hi/lo bf16 (double-buffered) -> A-frags are plain
// ds_read_b128, no per-step conversion, ONE barrier per step.
// ---------------------------------------------------------------------------
template<bool WORD, int TMAX>
__global__ __launch_bounds__(512, 2) void gru_mfma(
    const float* __restrict__ table,
    const int*   __restrict__ tokens,
    const int*   __restrict__ lengths,
    const int*   __restrict__ order,
    const float* __restrict__ Whh_f, const float* __restrict__ Whh_b,
    const float* __restrict__ bhh_f, const float* __restrict__ bhh_b,
    float* __restrict__ hout_f, float* __restrict__ hout_b,
    int numSeq, int numTiles)
{
    using bf16x8 = __attribute__((ext_vector_type(8))) short;
    using f32x4  = __attribute__((ext_vector_type(4))) float;

    const int dir  = (blockIdx.x >= numTiles) ? 1 : 0;
    const int rawt = dir ? (blockIdx.x - numTiles) : blockIdx.x;
    const int tile = numTiles - 1 - rawt;      // longest tiles first
    const int base = tile * 16;
    const int tid  = threadIdx.x;              // 0..511
    const int lane = tid & 63;
    const int wid  = tid >> 6;                 // 0..7
    const int rlane = lane & 15;
    const int kgrp  = lane >> 4;               // 0..3
    const int e = wid * 16 + rlane;            // this lane's gate element

    __shared__ __align__(16) short sh_hi[2][16][136];  // double-buffered split-h
    __shared__ __align__(16) short sh_lo[2][16][136];
    __shared__ int sh_len[16];
    __shared__ int sh_ord[16];
    __shared__ int sh_tok[WORD ? 16 * WW : 1];
    __shared__ int sh_maxlen;

    // ---- per-wave weight fragments: wave w -> cols {e-slice of r,z,n} ----
    const float* Whh = dir ? Whh_b : Whh_f;
    const float* bhh = dir ? bhh_b : bhh_f;
    bf16x8 Bhi[3][4], Blo[3][4];
    float bb[3];
    #pragma unroll
    for (int nt = 0; nt < 3; ++nt) {
        const int cb = nt * HDIM + wid * 16;   // gate col tile origin
        const float* wrow = Whh + (size_t)(cb + rlane) * HDIM;
        bb[nt] = bhh[cb + rlane];
        #pragma unroll
        for (int kc = 0; kc < 4; ++kc) {
            const float* wp = wrow + kc * 32 + kgrp * 8;
            float4 w0 = *(const float4*)wp;
            float4 w1 = *(const float4*)(wp + 4);
            float wv[8] = {w0.x, w0.y, w0.z, w0.w, w1.x, w1.y, w1.z, w1.w};
            #pragma unroll
            for (int j = 0; j < 8; ++j) {
                short hi = f2bf(wv[j]);
                Bhi[nt][kc][j] = hi;
                Blo[nt][kc][j] = f2bf(wv[j] - bf2f(hi));
            }
        }
    }

    // ---- tile metadata ----
    if (tid < 16) {
        int pos = base + tid;
        int seq = (pos < numSeq) ? order[pos] : -1;
        sh_ord[tid] = seq;
        sh_len[tid] = (seq >= 0) ? lengths[seq] : 0;
    }
    __syncthreads();
    if (WORD) {
        for (int f = tid; f < 16 * WW; f += 512) {
            int s = f >> 6;
            int seq = sh_ord[s];
            sh_tok[f] = (seq >= 0) ? tokens[(size_t)seq * WW + (f & 63)] : 0;
        }
    }
    // zero both h buffers
    for (int u = tid; u < 2 * 16 * 136; u += 512) {
        ((short*)sh_hi)[u] = 0;
        ((short*)sh_lo)[u] = 0;
    }
    if (tid == 0) {
        int m = 0;
        for (int s = 0; s < 16; ++s) m = max(m, sh_len[s]);
        sh_maxlen = m;
    }
    // per-lane seq metadata: this lane owns seqs {4*kgrp + j}
    int lens[4], ords[4];
    #pragma unroll
    for (int j = 0; j < 4; ++j) {
        lens[j] = sh_len[4 * kgrp + j];
        ords[j] = sh_ord[4 * kgrp + j];
    }
    __syncthreads();
    const int maxlen = sh_maxlen;

    // ---- xg gather: 3 f32 per owned seq at elem e ----
    auto fetch_xg = [&](int t, float* fr, float* fz, float* fn) {
        #pragma unroll
        for (int j = 0; j < 4; ++j) {
            fr[j] = 0.f; fz[j] = 0.f; fn[j] = 0.f;
            if (t < lens[j]) {
                int tt = dir ? (lens[j] - 1 - t) : t;
                size_t row;
                if (WORD) row = (size_t)sh_tok[(4 * kgrp + j) * WW + tt];
                else      row = (size_t)ords[j] * TMAX + tt;
                const float* xg = table + row * NPROJ + dir * G3 + e;
                fr[j] = xg[0]; fz[j] = xg[HDIM]; fn[j] = xg[2 * HDIM];
            }
        }
    };

    float hold[4] = {0.f, 0.f, 0.f, 0.f};
    float pr[4], pz[4], pn[4];
    fetch_xg(0, pr, pz, pn);

    for (int t = 0; t < maxlen; ++t) {
        const int cur = t & 1, nxt = cur ^ 1;
        // ---- A fragments: direct b128 reads of pre-split h ----
        bf16x8 ah[4], al[4];
        #pragma unroll
        for (int kc = 0; kc < 4; ++kc) {
            ah[kc] = *(const bf16x8*)&sh_hi[cur][rlane][kc * 32 + kgrp * 8];
            al[kc] = *(const bf16x8*)&sh_lo[cur][rlane][kc * 32 + kgrp * 8];
        }
        // ---- prefetch next step's xg (hides under MFMA + gate) ----
        float qr[4], qz[4], qn[4];
        fetch_xg(t + 1, qr, qz, qn);
        // ---- split-bf16 MFMA: hg slices for r,z,n at this lane's (seqs, e) ----
        f32x4 acc[3];
        #pragma unroll
        for (int nt = 0; nt < 3; ++nt) {
            acc[nt] = {0.f, 0.f, 0.f, 0.f};
            #pragma unroll
            for (int kc = 0; kc < 4; ++kc)
                acc[nt] = __builtin_amdgcn_mfma_f32_16x16x32_bf16(
                    ah[kc], Bhi[nt][kc], acc[nt], 0, 0, 0);
            #pragma unroll
            for (int kc = 0; kc < 4; ++kc)
                acc[nt] = __builtin_amdgcn_mfma_f32_16x16x32_bf16(
                    ah[kc], Blo[nt][kc], acc[nt], 0, 0, 0);
            #pragma unroll
            for (int kc = 0; kc < 4; ++kc)
                acc[nt] = __builtin_amdgcn_mfma_f32_16x16x32_bf16(
                    al[kc], Bhi[nt][kc], acc[nt], 0, 0, 0);
        }
        // ---- in-register gate update (seq = 4*kgrp + j matches C/D row) ----
        #pragma unroll
        for (int j = 0; j < 4; ++j) {
            if (t < lens[j]) {
                float hgr = acc[0][j] + bb[0];
                float hgz = acc[1][j] + bb[1];
                float hgn = acc[2][j] + bb[2];
                float rg = fsigmoid(pr[j] + hgr);
                float zg = fsigmoid(pz[j] + hgz);
                float ng = ftanh(pn[j] + rg * hgn);
                hold[j] = (1.f - zg) * ng + zg * hold[j];
            }
        }
        // ---- publish split h to next buffer (unconditional: value persists) ----
        #pragma unroll
        for (int j = 0; j < 4; ++j) {
            const int s = 4 * kgrp + j;
            short hi = f2bf(hold[j]);
            sh_hi[nxt][s][e] = hi;
            sh_lo[nxt][s][e] = f2bf(hold[j] - bf2f(hi));
        }
        #pragma unroll
        for (int j = 0; j < 4; ++j) { pr[j] = qr[j]; pz[j] = qz[j]; pn[j] = qn[j]; }
        __syncthreads();
    }

    // ---- write out last-h from registers ----
    float* hout = dir ? hout_b : hout_f;
    #pragma unroll
    for (int j = 0; j < 4; ++j) {
        if (ords[j] >= 0)
            hout[(size_t)ords[j] * HDIM + e] = hold[j];
    }
}

// ---------------------------------------------------------------------------
// Head + mean
// ---------------------------------------------------------------------------
__global__ __launch_bounds__(64) void head_kernel(
    const float* __restrict__ hsf, const float* __restrict__ hsb,
    const float* __restrict__ fc1_w, const float* __restrict__ fc1_b,
    const float* __restrict__ fc2_w, const float* __restrict__ fc2_b,
    float* __restrict__ out)
{
    const int br = blockIdx.x;
    const int j = threadIdx.x;
    __shared__ float rev[HDIM];
    for (int ee = j; ee < HDIM; ee += 64)
        rev[ee] = 0.5f * (hsf[(size_t)br * HDIM + ee] + hsb[(size_t)br * HDIM + ee]);
    __syncthreads();
    float acc = 0.f;
    #pragma unroll
    for (int k = 0; k < HDIM; ++k)
        acc = fmaf(fc1_w[(size_t)j * HDIM + k], rev[k], acc);
    acc += fc1_b[j];
    const float alpha = 1.6732632423543772f;
    const float scale = 1.0507009873554805f;
    float h1 = scale * (acc > 0.f ? acc : alpha * (expf(acc) - 1.f));
    float contrib = h1 * fc2_w[j];
    #pragma unroll
    for (int off = 32; off > 0; off >>= 1)
        contrib += __shfl_down(contrib, off);
    if (j == 0) out[16 + br] = contrib + fc2_b[0];
}

__global__ void mean_kernel(float* __restrict__ out)
{
    int b = threadIdx.x;
    if (b < BB) {
        float s = 0.f;
        for (int r = 0; r < RR; ++r) s += out[16 + b * RR + r];
        out[b] = s / (float)RR;
    }
}

// ---------------------------------------------------------------------------
// Launch
// ---------------------------------------------------------------------------
extern "C" void kernel_launch(void* const* d_in, const int* in_sizes, int n_in,
                              void* d_out, int out_size, void* d_ws, size_t ws_size,
                              hipStream_t stream)
{
    const int*   inputs       = (const int*)d_in[0];
    const int*   sent_lengths = (const int*)d_in[1];
    const int*   sent_counts  = (const int*)d_in[2];
    const float* embed   = (const float*)d_in[3];
    const float* wWih_f  = (const float*)d_in[4];
    const float* wWhh_f  = (const float*)d_in[5];
    const float* wbih_f  = (const float*)d_in[6];
    const float* wbhh_f  = (const float*)d_in[7];
    const float* wWih_b  = (const float*)d_in[8];
    const float* wWhh_b  = (const float*)d_in[9];
    const float* wbih_b  = (const float*)d_in[10];
    const float* wbhh_b  = (const float*)d_in[11];
    const float* sWih_f  = (const float*)d_in[12];
    const float* sWhh_f  = (const float*)d_in[13];
    const float* sbih_f  = (const float*)d_in[14];
    const float* sbhh_f  = (const float*)d_in[15];
    const float* sWih_b  = (const float*)d_in[16];
    const float* sWhh_b  = (const float*)d_in[17];
    const float* sbih_b  = (const float*)d_in[18];
    const float* sbhh_b  = (const float*)d_in[19];
    const float* fc1_w   = (const float*)d_in[20];
    const float* fc1_b   = (const float*)d_in[21];
    const float* fc2_w   = (const float*)d_in[22];
    const float* fc2_b   = (const float*)d_in[23];

    float* ws = (float*)d_ws;
    const size_t projT_elems = (size_t)VOCAB * NPROJ;
    const size_t xgs_elems   = (size_t)NSENT * NPROJ;
    const size_t h_elems     = (size_t)NSENT * HDIM;
    const size_t hs_elems    = (size_t)NREV * HDIM;
    float* projT = ws;
    float* xgs   = projT + projT_elems;
    float* hf    = xgs + xgs_elems;
    float* hb    = hf + h_elems;
    float* hsf   = hb + h_elems;
    float* hsb   = hsf + hs_elems;
    int* order1 = (int*)(hsb + hs_elems);          // [NSENT]
    int* hist1  = order1 + NSENT;                  // [65]
    int* order2 = hist1 + 65;                      // [NREV]
    int* hist2  = order2 + NREV;                   // [65]

    size_t need = (projT_elems + xgs_elems + 2*h_elems + 2*hs_elems) * sizeof(float)
                + (NSENT + NREV + 130) * sizeof(int);
    if (ws_size < need) return;

    // 0) counting sort of both length arrays
    sort_init<<<1, 65, 0, stream>>>(hist1);
    sort_init<<<1, 65, 0, stream>>>(hist2);
    sort_hist<<<(NSENT + 255) / 256, 256, 0, stream>>>(sent_lengths, NSENT, hist1);
    sort_hist<<<(NREV + 255) / 256, 256, 0, stream>>>(sent_counts, NREV, hist2);
    sort_scan<<<1, 1, 0, stream>>>(hist1, WW);
    sort_scan<<<1, 1, 0, stream>>>(hist2, SS);
    sort_scatter<<<(NSENT + 255) / 256, 256, 0, stream>>>(sent_lengths, NSENT, hist1, order1);
    sort_scatter<<<(NREV + 255) / 256, 256, 0, stream>>>(sent_counts, NREV, hist2, order2);

    // 1) projected-embedding table via split-bf16 MFMA
    {
        dim3 grid(NPROJ / 128, (VOCAB + 127) / 128);    // 6 x 391
        gemm_mfma_bias<<<grid, 256, 0, stream>>>(
            embed, VOCAB,
            wWih_f, wWih_b, wbih_f, wbih_b, projT);
    }
    // 2) word-level BiGRU last-h (fused-gate MFMA scan)
    {
        int numTiles = NSENT / 16;                      // 200
        gru_mfma<true, WW><<<2 * numTiles, 512, 0, stream>>>(
            projT, inputs, sent_lengths, order1,
            wWhh_f, wWhh_b, wbhh_f, wbhh_b,
            hf, hb, NSENT, numTiles);
    }
    // 3) sentence-level input projections (small, stays f32)
    {
        dim3 grid(NPROJ / TS, NSENT / TS);              // 12 x 50
        gemm2_bias<<<grid, 256, 0, stream>>>(
            hf, hb, NSENT, HDIM,
            sWih_f, sWih_b, sbih_f, sbih_b, xgs);
    }
    // 4) sentence-level BiGRU last-h (fused-gate MFMA scan)
    {
        int numTiles = NREV / 16;                       // 10
        gru_mfma<false, SS><<<2 * numTiles, 512, 0, stream>>>(
            xgs, nullptr, sent_counts, order2,
            sWhh_f, sWhh_b, sbhh_f, sbhh_b,
            hsf, hsb, NREV, numTiles);
    }
    // 5) FC head -> r_stars, then p_stars
    head_kernel<<<NREV, 64, 0, stream>>>(hsf, hsb, fc1_w, fc1_b, fc2_w, fc2_b,
                                         (float*)d_out);
    mean_kernel<<<1, 64, 0, stream>>>((float*)d_out);
}

// Round 8
// 358.290 us; speedup vs baseline: 4.1232x; 1.0106x over previous
//
#include <hip/hip_runtime.h>
#include <hip/hip_bf16.h>
#include <cstddef>

// ---------------------------------------------------------------------------
// Problem dims
// ---------------------------------------------------------------------------
#define VOCAB 50000
#define EDIM  200
#define HDIM  128
#define BB 16
#define RR 10
#define SS 20
#define WW 64
#define NSENT (BB*RR*SS)   // 3200 word-level sequences
#define NREV  (BB*RR)      // 160 sentence-level sequences
#define G3    (3*HDIM)     // 384 gate rows per direction
#define NPROJ (2*G3)       // 768

// ---------------------------------------------------------------------------
// bf16 helpers (RNE via bit trick)
// ---------------------------------------------------------------------------
static __device__ __forceinline__ short f2bf(float f) {
    union { float f; unsigned u; } v; v.f = f;
    unsigned r = v.u + 0x7FFFu + ((v.u >> 16) & 1u);
    return (short)(r >> 16);
}
static __device__ __forceinline__ float bf2f(short s) {
    union { unsigned u; float f; } v;
    v.u = ((unsigned)(unsigned short)s) << 16;
    return v.f;
}
static __device__ __forceinline__ float fsigmoid(float x) {
    return 1.f / (1.f + __expf(-x));
}
static __device__ __forceinline__ float ftanh(float x) {
    float xc = fminf(fmaxf(x, -15.f), 15.f);
    float e = __expf(-2.f * xc);
    return (1.f - e) / (1.f + e);
}

// ---------------------------------------------------------------------------
// Split-bf16 MFMA GEMM, templated on K:
//   C[M x 768] = A[M x KREAL] @ [B0;B1]^T + [bias0;bias1]
//   AVG: A row = 0.5*(A0+A1) (sentence-rep averaging)
// Tile 128x128, 256 threads (4 waves, each a 64x64 quadrant).
// ---------------------------------------------------------------------------
#define GM_LDK 40   // shorts per LDS row: 32 + 8 pad

template<int KREAL, int KPAD, bool AVG>
__global__ __launch_bounds__(256, 2) void gemm_mfma_bias(
    const float* __restrict__ A0, const float* __restrict__ A1, int M,
    const float* __restrict__ B0, const float* __restrict__ B1,
    const float* __restrict__ bias0, const float* __restrict__ bias1,
    float* __restrict__ C)
{
    using bf16x8 = __attribute__((ext_vector_type(8))) short;
    using f32x4  = __attribute__((ext_vector_type(4))) float;

    const int ct = blockIdx.x;
    const int rt = blockIdx.y;
    const int tid = threadIdx.x;
    const int lane = tid & 63;
    const int wid  = tid >> 6;
    const int rlane = lane & 15;
    const int kgrp  = lane >> 4;

    const int rowBase = rt * 128;
    const int colBase = ct * 128;
    const float* Bsrc = (colBase < G3) ? B0 : B1;
    const int bcol = (colBase < G3) ? colBase : (colBase - G3);

    __shared__ short Ahi[128][GM_LDK], Alo[128][GM_LDK];
    __shared__ short Bhi[128][GM_LDK], Blo[128][GM_LDK];

    const int wrow = (wid >> 1) * 64;
    const int wcol = (wid & 1) * 64;

    f32x4 acc[4][4];
    #pragma unroll
    for (int i = 0; i < 4; ++i)
        #pragma unroll
        for (int j = 0; j < 4; ++j) acc[i][j] = {0.f, 0.f, 0.f, 0.f};

    const int srow = tid >> 1;
    const int skh  = (tid & 1) << 4;

    for (int k0 = 0; k0 < KPAD; k0 += 32) {
        {
            const int grow = rowBase + srow;
            float v[16];
            #pragma unroll
            for (int i = 0; i < 4; ++i) {
                const int k = k0 + skh + i * 4;
                float4 x = {0.f, 0.f, 0.f, 0.f};
                if (grow < M && k + 3 < KREAL) {
                    x = *(const float4*)&A0[(size_t)grow * KREAL + k];
                    if (AVG) {
                        float4 y = *(const float4*)&A1[(size_t)grow * KREAL + k];
                        x.x = 0.5f * (x.x + y.x); x.y = 0.5f * (x.y + y.y);
                        x.z = 0.5f * (x.z + y.z); x.w = 0.5f * (x.w + y.w);
                    }
                }
                v[4*i+0] = x.x; v[4*i+1] = x.y; v[4*i+2] = x.z; v[4*i+3] = x.w;
            }
            bf16x8 h0, h1, l0, l1;
            #pragma unroll
            for (int i = 0; i < 8; ++i) {
                short a = f2bf(v[i]);
                h0[i] = a; l0[i] = f2bf(v[i] - bf2f(a));
                short b = f2bf(v[i + 8]);
                h1[i] = b; l1[i] = f2bf(v[i + 8] - bf2f(b));
            }
            *(bf16x8*)&Ahi[srow][skh]     = h0;
            *(bf16x8*)&Ahi[srow][skh + 8] = h1;
            *(bf16x8*)&Alo[srow][skh]     = l0;
            *(bf16x8*)&Alo[srow][skh + 8] = l1;
        }
        {
            const int gcol = bcol + srow;
            float v[16];
            #pragma unroll
            for (int i = 0; i < 4; ++i) {
                const int k = k0 + skh + i * 4;
                float4 x = {0.f, 0.f, 0.f, 0.f};
                if (k + 3 < KREAL)
                    x = *(const float4*)&Bsrc[(size_t)gcol * KREAL + k];
                v[4*i+0] = x.x; v[4*i+1] = x.y; v[4*i+2] = x.z; v[4*i+3] = x.w;
            }
            bf16x8 h0, h1, l0, l1;
            #pragma unroll
            for (int i = 0; i < 8; ++i) {
                short a = f2bf(v[i]);
                h0[i] = a; l0[i] = f2bf(v[i] - bf2f(a));
                short b = f2bf(v[i + 8]);
                h1[i] = b; l1[i] = f2bf(v[i + 8] - bf2f(b));
            }
            *(bf16x8*)&Bhi[srow][skh]     = h0;
            *(bf16x8*)&Bhi[srow][skh + 8] = h1;
            *(bf16x8*)&Blo[srow][skh]     = l0;
            *(bf16x8*)&Blo[srow][skh + 8] = l1;
        }
        __syncthreads();
        bf16x8 ah[4], al[4], bh[4], bl[4];
        #pragma unroll
        for (int mr = 0; mr < 4; ++mr) {
            ah[mr] = *(const bf16x8*)&Ahi[wrow + mr * 16 + rlane][kgrp * 8];
            al[mr] = *(const bf16x8*)&Alo[wrow + mr * 16 + rlane][kgrp * 8];
        }
        #pragma unroll
        for (int nc = 0; nc < 4; ++nc) {
            bh[nc] = *(const bf16x8*)&Bhi[wcol + nc * 16 + rlane][kgrp * 8];
            bl[nc] = *(const bf16x8*)&Blo[wcol + nc * 16 + rlane][kgrp * 8];
        }
        #pragma unroll
        for (int mr = 0; mr < 4; ++mr)
            #pragma unroll
            for (int nc = 0; nc < 4; ++nc) {
                acc[mr][nc] = __builtin_amdgcn_mfma_f32_16x16x32_bf16(
                    ah[mr], bh[nc], acc[mr][nc], 0, 0, 0);
                acc[mr][nc] = __builtin_amdgcn_mfma_f32_16x16x32_bf16(
                    ah[mr], bl[nc], acc[mr][nc], 0, 0, 0);
                acc[mr][nc] = __builtin_amdgcn_mfma_f32_16x16x32_bf16(
                    al[mr], bh[nc], acc[mr][nc], 0, 0, 0);
            }
        __syncthreads();
    }

    const float* bs = (colBase < G3) ? bias0 : bias1;
    #pragma unroll
    for (int nc = 0; nc < 4; ++nc) {
        const int c = wcol + nc * 16 + rlane;
        const float bv = bs[bcol + c];
        #pragma unroll
        for (int mr = 0; mr < 4; ++mr) {
            #pragma unroll
            for (int r = 0; r < 4; ++r) {
                const int grow = rowBase + wrow + mr * 16 + kgrp * 4 + r;
                if (grow < M)
                    C[(size_t)grow * NPROJ + colBase + c] = acc[mr][nc][r] + bv;
            }
        }
    }
}

// ---------------------------------------------------------------------------
// Counting sort by length
// ---------------------------------------------------------------------------
__global__ void sort_init(int* hist) {
    if (threadIdx.x < 65) hist[threadIdx.x] = 0;
}
__global__ void sort_hist(const int* __restrict__ lengths, int n, int* hist) {
    int i = blockIdx.x * 256 + threadIdx.x;
    if (i < n) atomicAdd(&hist[lengths[i]], 1);
}
__global__ void sort_scan(int* hist, int maxlen) {
    if (threadIdx.x == 0) {
        int acc = 0;
        for (int l = 1; l <= maxlen; ++l) { int c = hist[l]; hist[l] = acc; acc += c; }
    }
}
__global__ void sort_scatter(const int* __restrict__ lengths, int n,
                             int* hist, int* order) {
    int i = blockIdx.x * 256 + threadIdx.x;
    if (i < n) {
        int pos = atomicAdd(&hist[lengths[i]], 1);
        order[pos] = i;
    }
}

// ---------------------------------------------------------------------------
// MFMA GRU scan, fused-gate, depth-2 xg prefetch, 9-chain MFMA.
// One block = (tile of 16 sorted seqs, direction); 512 threads = 8 waves.
// Wave w owns gate cols {w*16 (r), 128+w*16 (z), 256+w*16 (n)}; gate update
// fully in-register; h state in regs; h published to LDS as pre-split
// hi/lo bf16 (double-buffered); ONE barrier per step.
// Latency structure: xg gather prefetched 2 steps ahead (p/q/r rotation);
// each gate's MFMA split into 3 independent 4-deep chains (hh, hl, lh)
// summed after -> dependency depth 4 instead of 12.
// ---------------------------------------------------------------------------
template<bool WORD, int TMAX>
__global__ __launch_bounds__(512, 2) void gru_mfma(
    const float* __restrict__ table,
    const int*   __restrict__ tokens,
    const int*   __restrict__ lengths,
    const int*   __restrict__ order,
    const float* __restrict__ Whh_f, const float* __restrict__ Whh_b,
    const float* __restrict__ bhh_f, const float* __restrict__ bhh_b,
    float* __restrict__ hout_f, float* __restrict__ hout_b,
    int numSeq, int numTiles)
{
    using bf16x8 = __attribute__((ext_vector_type(8))) short;
    using f32x4  = __attribute__((ext_vector_type(4))) float;

    const int dir  = (blockIdx.x >= numTiles) ? 1 : 0;
    const int rawt = dir ? (blockIdx.x - numTiles) : blockIdx.x;
    const int tile = numTiles - 1 - rawt;      // longest tiles first
    const int base = tile * 16;
    const int tid  = threadIdx.x;              // 0..511
    const int lane = tid & 63;
    const int wid  = tid >> 6;                 // 0..7
    const int rlane = lane & 15;
    const int kgrp  = lane >> 4;               // 0..3
    const int e = wid * 16 + rlane;            // this lane's gate element

    __shared__ __align__(16) short sh_hi[2][16][136];
    __shared__ __align__(16) short sh_lo[2][16][136];
    __shared__ int sh_len[16];
    __shared__ int sh_ord[16];
    __shared__ int sh_tok[WORD ? 16 * WW : 1];
    __shared__ int sh_maxlen;

    // ---- per-wave weight fragments ----
    const float* Whh = dir ? Whh_b : Whh_f;
    const float* bhh = dir ? bhh_b : bhh_f;
    bf16x8 Bhi[3][4], Blo[3][4];
    float bb[3];
    #pragma unroll
    for (int nt = 0; nt < 3; ++nt) {
        const int cb = nt * HDIM + wid * 16;
        const float* wrow = Whh + (size_t)(cb + rlane) * HDIM;
        bb[nt] = bhh[cb + rlane];
        #pragma unroll
        for (int kc = 0; kc < 4; ++kc) {
            const float* wp = wrow + kc * 32 + kgrp * 8;
            float4 w0 = *(const float4*)wp;
            float4 w1 = *(const float4*)(wp + 4);
            float wv[8] = {w0.x, w0.y, w0.z, w0.w, w1.x, w1.y, w1.z, w1.w};
            #pragma unroll
            for (int j = 0; j < 8; ++j) {
                short hi = f2bf(wv[j]);
                Bhi[nt][kc][j] = hi;
                Blo[nt][kc][j] = f2bf(wv[j] - bf2f(hi));
            }
        }
    }

    // ---- tile metadata ----
    if (tid < 16) {
        int pos = base + tid;
        int seq = (pos < numSeq) ? order[pos] : -1;
        sh_ord[tid] = seq;
        sh_len[tid] = (seq >= 0) ? lengths[seq] : 0;
    }
    __syncthreads();
    if (WORD) {
        for (int f = tid; f < 16 * WW; f += 512) {
            int s = f >> 6;
            int seq = sh_ord[s];
            sh_tok[f] = (seq >= 0) ? tokens[(size_t)seq * WW + (f & 63)] : 0;
        }
    }
    for (int u = tid; u < 2 * 16 * 136; u += 512) {
        ((short*)sh_hi)[u] = 0;
        ((short*)sh_lo)[u] = 0;
    }
    if (tid == 0) {
        int m = 0;
        for (int s = 0; s < 16; ++s) m = max(m, sh_len[s]);
        sh_maxlen = m;
    }
    int lens[4], ords[4];
    #pragma unroll
    for (int j = 0; j < 4; ++j) {
        lens[j] = sh_len[4 * kgrp + j];
        ords[j] = sh_ord[4 * kgrp + j];
    }
    __syncthreads();
    const int maxlen = sh_maxlen;

    auto fetch_xg = [&](int t, float* fr, float* fz, float* fn) {
        #pragma unroll
        for (int j = 0; j < 4; ++j) {
            fr[j] = 0.f; fz[j] = 0.f; fn[j] = 0.f;
            if (t < lens[j]) {
                int tt = dir ? (lens[j] - 1 - t) : t;
                size_t row;
                if (WORD) row = (size_t)sh_tok[(4 * kgrp + j) * WW + tt];
                else      row = (size_t)ords[j] * TMAX + tt;
                const float* xg = table + row * NPROJ + dir * G3 + e;
                fr[j] = xg[0]; fz[j] = xg[HDIM]; fn[j] = xg[2 * HDIM];
            }
        }
    };

    float hold[4] = {0.f, 0.f, 0.f, 0.f};
    float pr[4], pz[4], pn[4];     // xg for step t
    float qr[4], qz[4], qn[4];     // xg for step t+1
    fetch_xg(0, pr, pz, pn);
    fetch_xg(1, qr, qz, qn);

    for (int t = 0; t < maxlen; ++t) {
        const int cur = t & 1, nxt = cur ^ 1;
        // ---- A fragments: direct b128 reads of pre-split h ----
        bf16x8 ah[4], al[4];
        #pragma unroll
        for (int kc = 0; kc < 4; ++kc) {
            ah[kc] = *(const bf16x8*)&sh_hi[cur][rlane][kc * 32 + kgrp * 8];
            al[kc] = *(const bf16x8*)&sh_lo[cur][rlane][kc * 32 + kgrp * 8];
        }
        // ---- prefetch xg for step t+2 (two full phases of slack) ----
        float rr[4], rz[4], rn[4];
        fetch_xg(t + 2, rr, rz, rn);
        // ---- split-bf16 MFMA: 3 gates x 3 independent 4-deep chains ----
        f32x4 ahh[3], ahl[3], alh[3];
        #pragma unroll
        for (int nt = 0; nt < 3; ++nt) {
            ahh[nt] = {0.f, 0.f, 0.f, 0.f};
            ahl[nt] = {0.f, 0.f, 0.f, 0.f};
            alh[nt] = {0.f, 0.f, 0.f, 0.f};
            #pragma unroll
            for (int kc = 0; kc < 4; ++kc) {
                ahh[nt] = __builtin_amdgcn_mfma_f32_16x16x32_bf16(
                    ah[kc], Bhi[nt][kc], ahh[nt], 0, 0, 0);
                ahl[nt] = __builtin_amdgcn_mfma_f32_16x16x32_bf16(
                    ah[kc], Blo[nt][kc], ahl[nt], 0, 0, 0);
                alh[nt] = __builtin_amdgcn_mfma_f32_16x16x32_bf16(
                    al[kc], Bhi[nt][kc], alh[nt], 0, 0, 0);
            }
        }
        // ---- in-register gate update ----
        #pragma unroll
        for (int j = 0; j < 4; ++j) {
            if (t < lens[j]) {
                float hgr = ahh[0][j] + ahl[0][j] + alh[0][j] + bb[0];
                float hgz = ahh[1][j] + ahl[1][j] + alh[1][j] + bb[1];
                float hgn = ahh[2][j] + ahl[2][j] + alh[2][j] + bb[2];
                float rg = fsigmoid(pr[j] + hgr);
                float zg = fsigmoid(pz[j] + hgz);
                float ng = ftanh(pn[j] + rg * hgn);
                hold[j] = (1.f - zg) * ng + zg * hold[j];
            }
        }
        // ---- publish split h to next buffer ----
        #pragma unroll
        for (int j = 0; j < 4; ++j) {
            const int s = 4 * kgrp + j;
            short hi = f2bf(hold[j]);
            sh_hi[nxt][s][e] = hi;
            sh_lo[nxt][s][e] = f2bf(hold[j] - bf2f(hi));
        }
        // ---- rotate xg pipeline ----
        #pragma unroll
        for (int j = 0; j < 4; ++j) {
            pr[j] = qr[j]; pz[j] = qz[j]; pn[j] = qn[j];
            qr[j] = rr[j]; qz[j] = rz[j]; qn[j] = rn[j];
        }
        __syncthreads();
    }

    // ---- write out last-h from registers ----
    float* hout = dir ? hout_b : hout_f;
    #pragma unroll
    for (int j = 0; j < 4; ++j) {
        if (ords[j] >= 0)
            hout[(size_t)ords[j] * HDIM + e] = hold[j];
    }
}

// ---------------------------------------------------------------------------
// Head + mean
// ---------------------------------------------------------------------------
__global__ __launch_bounds__(64) void head_kernel(
    const float* __restrict__ hsf, const float* __restrict__ hsb,
    const float* __restrict__ fc1_w, const float* __restrict__ fc1_b,
    const float* __restrict__ fc2_w, const float* __restrict__ fc2_b,
    float* __restrict__ out)
{
    const int br = blockIdx.x;
    const int j = threadIdx.x;
    __shared__ float rev[HDIM];
    for (int ee = j; ee < HDIM; ee += 64)
        rev[ee] = 0.5f * (hsf[(size_t)br * HDIM + ee] + hsb[(size_t)br * HDIM + ee]);
    __syncthreads();
    float acc = 0.f;
    #pragma unroll
    for (int k = 0; k < HDIM; ++k)
        acc = fmaf(fc1_w[(size_t)j * HDIM + k], rev[k], acc);
    acc += fc1_b[j];
    const float alpha = 1.6732632423543772f;
    const float scale = 1.0507009873554805f;
    float h1 = scale * (acc > 0.f ? acc : alpha * (expf(acc) - 1.f));
    float contrib = h1 * fc2_w[j];
    #pragma unroll
    for (int off = 32; off > 0; off >>= 1)
        contrib += __shfl_down(contrib, off);
    if (j == 0) out[16 + br] = contrib + fc2_b[0];
}

__global__ void mean_kernel(float* __restrict__ out)
{
    int b = threadIdx.x;
    if (b < BB) {
        float s = 0.f;
        for (int r = 0; r < RR; ++r) s += out[16 + b * RR + r];
        out[b] = s / (float)RR;
    }
}

// ---------------------------------------------------------------------------
// Launch
// ---------------------------------------------------------------------------
extern "C" void kernel_launch(void* const* d_in, const int* in_sizes, int n_in,
                              void* d_out, int out_size, void* d_ws, size_t ws_size,
                              hipStream_t stream)
{
    const int*   inputs       = (const int*)d_in[0];
    const int*   sent_lengths = (const int*)d_in[1];
    const int*   sent_counts  = (const int*)d_in[2];
    const float* embed   = (const float*)d_in[3];
    const float* wWih_f  = (const float*)d_in[4];
    const float* wWhh_f  = (const float*)d_in[5];
    const float* wbih_f  = (const float*)d_in[6];
    const float* wbhh_f  = (const float*)d_in[7];
    const float* wWih_b  = (const float*)d_in[8];
    const float* wWhh_b  = (const float*)d_in[9];
    const float* wbih_b  = (const float*)d_in[10];
    const float* wbhh_b  = (const float*)d_in[11];
    const float* sWih_f  = (const float*)d_in[12];
    const float* sWhh_f  = (const float*)d_in[13];
    const float* sbih_f  = (const float*)d_in[14];
    const float* sbhh_f  = (const float*)d_in[15];
    const float* sWih_b  = (const float*)d_in[16];
    const float* sWhh_b  = (const float*)d_in[17];
    const float* sbih_b  = (const float*)d_in[18];
    const float* sbhh_b  = (const float*)d_in[19];
    const float* fc1_w   = (const float*)d_in[20];
    const float* fc1_b   = (const float*)d_in[21];
    const float* fc2_w   = (const float*)d_in[22];
    const float* fc2_b   = (const float*)d_in[23];

    float* ws = (float*)d_ws;
    const size_t projT_elems = (size_t)VOCAB * NPROJ;
    const size_t xgs_elems   = (size_t)NSENT * NPROJ;
    const size_t h_elems     = (size_t)NSENT * HDIM;
    const size_t hs_elems    = (size_t)NREV * HDIM;
    float* projT = ws;
    float* xgs   = projT + projT_elems;
    float* hf    = xgs + xgs_elems;
    float* hb    = hf + h_elems;
    float* hsf   = hb + h_elems;
    float* hsb   = hsf + hs_elems;
    int* order1 = (int*)(hsb + hs_elems);          // [NSENT]
    int* hist1  = order1 + NSENT;                  // [65]
    int* order2 = hist1 + 65;                      // [NREV]
    int* hist2  = order2 + NREV;                   // [65]

    size_t need = (projT_elems + xgs_elems + 2*h_elems + 2*hs_elems) * sizeof(float)
                + (NSENT + NREV + 130) * sizeof(int);
    if (ws_size < need) return;

    // 0) counting sort of both length arrays
    sort_init<<<1, 65, 0, stream>>>(hist1);
    sort_init<<<1, 65, 0, stream>>>(hist2);
    sort_hist<<<(NSENT + 255) / 256, 256, 0, stream>>>(sent_lengths, NSENT, hist1);
    sort_hist<<<(NREV + 255) / 256, 256, 0, stream>>>(sent_counts, NREV, hist2);
    sort_scan<<<1, 1, 0, stream>>>(hist1, WW);
    sort_scan<<<1, 1, 0, stream>>>(hist2, SS);
    sort_scatter<<<(NSENT + 255) / 256, 256, 0, stream>>>(sent_lengths, NSENT, hist1, order1);
    sort_scatter<<<(NREV + 255) / 256, 256, 0, stream>>>(sent_counts, NREV, hist2, order2);

    // 1) projected-embedding table via split-bf16 MFMA (K=200 pad 224)
    {
        dim3 grid(NPROJ / 128, (VOCAB + 127) / 128);    // 6 x 391
        gemm_mfma_bias<EDIM, 224, false><<<grid, 256, 0, stream>>>(
            embed, nullptr, VOCAB,
            wWih_f, wWih_b, wbih_f, wbih_b, projT);
    }
    // 2) word-level BiGRU last-h (fused-gate MFMA scan)
    {
        int numTiles = NSENT / 16;                      // 200
        gru_mfma<true, WW><<<2 * numTiles, 512, 0, stream>>>(
            projT, inputs, sent_lengths, order1,
            wWhh_f, wWhh_b, wbhh_f, wbhh_b,
            hf, hb, NSENT, numTiles);
    }
    // 3) sentence-level input projections via split-bf16 MFMA (K=128, avg)
    {
        dim3 grid(NPROJ / 128, (NSENT + 127) / 128);    // 6 x 25
        gemm_mfma_bias<HDIM, HDIM, true><<<grid, 256, 0, stream>>>(
            hf, hb, NSENT,
            sWih_f, sWih_b, sbih_f, sbih_b, xgs);
    }
    // 4) sentence-level BiGRU last-h (fused-gate MFMA scan)
    {
        int numTiles = NREV / 16;                       // 10
        gru_mfma<false, SS><<<2 * numTiles, 512, 0, stream>>>(
            xgs, nullptr, sent_counts, order2,
            sWhh_f, sWhh_b, sbhh_f, sbhh_b,
            hsf, hsb, NREV, numTiles);
    }
    // 5) FC head -> r_stars, then p_stars
    head_kernel<<<NREV, 64, 0, stream>>>(hsf, hsb, fc1_w, fc1_b, fc2_w, fc2_b,
                                         (float*)d_out);
    mean_kernel<<<1, 64, 0, stream>>>((float*)d_out);
}

// Round 9
// 316.370 us; speedup vs baseline: 4.6695x; 1.1325x over previous
//
#include <hip/hip_runtime.h>
#include <hip/hip_bf16.h>
#include <cstddef>

// ---------------------------------------------------------------------------
// Problem dims
// ---------------------------------------------------------------------------
#define VOCAB 50000
#define EDIM  200
#define HDIM  128
#define BB 16
#define RR 10
#define SS 20
#define WW 64
#define NSENT (BB*RR*SS)   // 3200 word-level sequences
#define NREV  (BB*RR)      // 160 sentence-level sequences
#define G3    (3*HDIM)     // 384 gate rows per direction
#define NPROJ (2*G3)       // 768

// ---------------------------------------------------------------------------
// bf16 helpers (RNE via bit trick)
// ---------------------------------------------------------------------------
static __device__ __forceinline__ short f2bf(float f) {
    union { float f; unsigned u; } v; v.f = f;
    unsigned r = v.u + 0x7FFFu + ((v.u >> 16) & 1u);
    return (short)(r >> 16);
}
static __device__ __forceinline__ float bf2f(short s) {
    union { unsigned u; float f; } v;
    v.u = ((unsigned)(unsigned short)s) << 16;
    return v.f;
}
static __device__ __forceinline__ float fsigmoid(float x) {
    return 1.f / (1.f + __expf(-x));
}
static __device__ __forceinline__ float ftanh(float x) {
    float xc = fminf(fmaxf(x, -15.f), 15.f);
    float e = __expf(-2.f * xc);
    return (1.f - e) / (1.f + e);
}

// ---------------------------------------------------------------------------
// Split-bf16 MFMA GEMM, templated on K (unchanged from round 7):
//   C[M x 768] = A[M x KREAL] @ [B0;B1]^T + [bias0;bias1]
// ---------------------------------------------------------------------------
#define GM_LDK 40   // shorts per LDS row: 32 + 8 pad

template<int KREAL, int KPAD, bool AVG>
__global__ __launch_bounds__(256, 2) void gemm_mfma_bias(
    const float* __restrict__ A0, const float* __restrict__ A1, int M,
    const float* __restrict__ B0, const float* __restrict__ B1,
    const float* __restrict__ bias0, const float* __restrict__ bias1,
    float* __restrict__ C)
{
    using bf16x8 = __attribute__((ext_vector_type(8))) short;
    using f32x4  = __attribute__((ext_vector_type(4))) float;

    const int ct = blockIdx.x;
    const int rt = blockIdx.y;
    const int tid = threadIdx.x;
    const int lane = tid & 63;
    const int wid  = tid >> 6;
    const int rlane = lane & 15;
    const int kgrp  = lane >> 4;

    const int rowBase = rt * 128;
    const int colBase = ct * 128;
    const float* Bsrc = (colBase < G3) ? B0 : B1;
    const int bcol = (colBase < G3) ? colBase : (colBase - G3);

    __shared__ short Ahi[128][GM_LDK], Alo[128][GM_LDK];
    __shared__ short Bhi[128][GM_LDK], Blo[128][GM_LDK];

    const int wrow = (wid >> 1) * 64;
    const int wcol = (wid & 1) * 64;

    f32x4 acc[4][4];
    #pragma unroll
    for (int i = 0; i < 4; ++i)
        #pragma unroll
        for (int j = 0; j < 4; ++j) acc[i][j] = {0.f, 0.f, 0.f, 0.f};

    const int srow = tid >> 1;
    const int skh  = (tid & 1) << 4;

    for (int k0 = 0; k0 < KPAD; k0 += 32) {
        {
            const int grow = rowBase + srow;
            float v[16];
            #pragma unroll
            for (int i = 0; i < 4; ++i) {
                const int k = k0 + skh + i * 4;
                float4 x = {0.f, 0.f, 0.f, 0.f};
                if (grow < M && k + 3 < KREAL) {
                    x = *(const float4*)&A0[(size_t)grow * KREAL + k];
                    if (AVG) {
                        float4 y = *(const float4*)&A1[(size_t)grow * KREAL + k];
                        x.x = 0.5f * (x.x + y.x); x.y = 0.5f * (x.y + y.y);
                        x.z = 0.5f * (x.z + y.z); x.w = 0.5f * (x.w + y.w);
                    }
                }
                v[4*i+0] = x.x; v[4*i+1] = x.y; v[4*i+2] = x.z; v[4*i+3] = x.w;
            }
            bf16x8 h0, h1, l0, l1;
            #pragma unroll
            for (int i = 0; i < 8; ++i) {
                short a = f2bf(v[i]);
                h0[i] = a; l0[i] = f2bf(v[i] - bf2f(a));
                short b = f2bf(v[i + 8]);
                h1[i] = b; l1[i] = f2bf(v[i + 8] - bf2f(b));
            }
            *(bf16x8*)&Ahi[srow][skh]     = h0;
            *(bf16x8*)&Ahi[srow][skh + 8] = h1;
            *(bf16x8*)&Alo[srow][skh]     = l0;
            *(bf16x8*)&Alo[srow][skh + 8] = l1;
        }
        {
            const int gcol = bcol + srow;
            float v[16];
            #pragma unroll
            for (int i = 0; i < 4; ++i) {
                const int k = k0 + skh + i * 4;
                float4 x = {0.f, 0.f, 0.f, 0.f};
                if (k + 3 < KREAL)
                    x = *(const float4*)&Bsrc[(size_t)gcol * KREAL + k];
                v[4*i+0] = x.x; v[4*i+1] = x.y; v[4*i+2] = x.z; v[4*i+3] = x.w;
            }
            bf16x8 h0, h1, l0, l1;
            #pragma unroll
            for (int i = 0; i < 8; ++i) {
                short a = f2bf(v[i]);
                h0[i] = a; l0[i] = f2bf(v[i] - bf2f(a));
                short b = f2bf(v[i + 8]);
                h1[i] = b; l1[i] = f2bf(v[i + 8] - bf2f(b));
            }
            *(bf16x8*)&Bhi[srow][skh]     = h0;
            *(bf16x8*)&Bhi[srow][skh + 8] = h1;
            *(bf16x8*)&Blo[srow][skh]     = l0;
            *(bf16x8*)&Blo[srow][skh + 8] = l1;
        }
        __syncthreads();
        bf16x8 ah[4], al[4], bh[4], bl[4];
        #pragma unroll
        for (int mr = 0; mr < 4; ++mr) {
            ah[mr] = *(const bf16x8*)&Ahi[wrow + mr * 16 + rlane][kgrp * 8];
            al[mr] = *(const bf16x8*)&Alo[wrow + mr * 16 + rlane][kgrp * 8];
        }
        #pragma unroll
        for (int nc = 0; nc < 4; ++nc) {
            bh[nc] = *(const bf16x8*)&Bhi[wcol + nc * 16 + rlane][kgrp * 8];
            bl[nc] = *(const bf16x8*)&Blo[wcol + nc * 16 + rlane][kgrp * 8];
        }
        #pragma unroll
        for (int mr = 0; mr < 4; ++mr)
            #pragma unroll
            for (int nc = 0; nc < 4; ++nc) {
                acc[mr][nc] = __builtin_amdgcn_mfma_f32_16x16x32_bf16(
                    ah[mr], bh[nc], acc[mr][nc], 0, 0, 0);
                acc[mr][nc] = __builtin_amdgcn_mfma_f32_16x16x32_bf16(
                    ah[mr], bl[nc], acc[mr][nc], 0, 0, 0);
                acc[mr][nc] = __builtin_amdgcn_mfma_f32_16x16x32_bf16(
                    al[mr], bh[nc], acc[mr][nc], 0, 0, 0);
            }
        __syncthreads();
    }

    const float* bs = (colBase < G3) ? bias0 : bias1;
    #pragma unroll
    for (int nc = 0; nc < 4; ++nc) {
        const int c = wcol + nc * 16 + rlane;
        const float bv = bs[bcol + c];
        #pragma unroll
        for (int mr = 0; mr < 4; ++mr) {
            #pragma unroll
            for (int r = 0; r < 4; ++r) {
                const int grow = rowBase + wrow + mr * 16 + kgrp * 4 + r;
                if (grow < M)
                    C[(size_t)grow * NPROJ + colBase + c] = acc[mr][nc][r] + bv;
            }
        }
    }
}

// ---------------------------------------------------------------------------
// Single-block counting sort for BOTH length arrays (replaces 8 launches).
// Order within a bucket is nondeterministic but results are per-sequence.
// ---------------------------------------------------------------------------
__global__ __launch_bounds__(256) void sort_all(
    const int* __restrict__ len1, int* __restrict__ order1,
    const int* __restrict__ len2, int* __restrict__ order2)
{
    __shared__ int hist[65];
    const int tid = threadIdx.x;

    // --- array 1 ---
    for (int i = tid; i < 65; i += 256) hist[i] = 0;
    __syncthreads();
    for (int i = tid; i < NSENT; i += 256) atomicAdd(&hist[len1[i]], 1);
    __syncthreads();
    if (tid == 0) {
        int acc = 0;
        for (int l = 1; l <= WW; ++l) { int c = hist[l]; hist[l] = acc; acc += c; }
    }
    __syncthreads();
    for (int i = tid; i < NSENT; i += 256) {
        int pos = atomicAdd(&hist[len1[i]], 1);
        order1[pos] = i;
    }
    __syncthreads();
    // --- array 2 ---
    for (int i = tid; i < 65; i += 256) hist[i] = 0;
    __syncthreads();
    for (int i = tid; i < NREV; i += 256) atomicAdd(&hist[len2[i]], 1);
    __syncthreads();
    if (tid == 0) {
        int acc = 0;
        for (int l = 1; l <= SS; ++l) { int c = hist[l]; hist[l] = acc; acc += c; }
    }
    __syncthreads();
    for (int i = tid; i < NREV; i += 256) {
        int pos = atomicAdd(&hist[len2[i]], 1);
        order2[pos] = i;
    }
}

// ---------------------------------------------------------------------------
// MFMA GRU scan, fused-gate, TRUE depth-2 xg prefetch via 2-body unroll.
// One block = (tile of 16 sorted seqs, direction); 512 threads = 8 waves.
// Wave w owns gate cols {w*16 (r), 128+w*16 (z), 256+w*16 (n)}; gate update
// fully in-register; h state in regs; h published to LDS as pre-split
// hi/lo bf16 (double-buffered); ONE barrier per step.
// Prefetch: two named register sets pA/pB; body(t) consumes its set at the
// gate and re-fetches xg(t+2) into the SAME (now dead) set -> the load is
// loop-carried, waitcnt lands ~2 steps after issue, no register rotation.
// Single 12-deep MFMA chain per gate (12 acc regs) — cross-wave overlap
// hides MFMA latency; low register pressure.
// ---------------------------------------------------------------------------
template<bool WORD, int TMAX>
__global__ __launch_bounds__(512, 2) void gru_mfma(
    const float* __restrict__ table,
    const int*   __restrict__ tokens,
    const int*   __restrict__ lengths,
    const int*   __restrict__ order,
    const float* __restrict__ Whh_f, const float* __restrict__ Whh_b,
    const float* __restrict__ bhh_f, const float* __restrict__ bhh_b,
    float* __restrict__ hout_f, float* __restrict__ hout_b,
    int numSeq, int numTiles)
{
    using bf16x8 = __attribute__((ext_vector_type(8))) short;
    using f32x4  = __attribute__((ext_vector_type(4))) float;

    const int dir  = (blockIdx.x >= numTiles) ? 1 : 0;
    const int rawt = dir ? (blockIdx.x - numTiles) : blockIdx.x;
    const int tile = numTiles - 1 - rawt;      // longest tiles first
    const int base = tile * 16;
    const int tid  = threadIdx.x;              // 0..511
    const int lane = tid & 63;
    const int wid  = tid >> 6;                 // 0..7
    const int rlane = lane & 15;
    const int kgrp  = lane >> 4;               // 0..3
    const int e = wid * 16 + rlane;            // this lane's gate element

    __shared__ __align__(16) short sh_hi[2][16][136];
    __shared__ __align__(16) short sh_lo[2][16][136];
    __shared__ int sh_len[16];
    __shared__ int sh_ord[16];
    __shared__ int sh_tok[WORD ? 16 * WW : 1];
    __shared__ int sh_maxlen;

    // ---- per-wave weight fragments ----
    const float* Whh = dir ? Whh_b : Whh_f;
    const float* bhh = dir ? bhh_b : bhh_f;
    bf16x8 Bhi[3][4], Blo[3][4];
    float bb[3];
    #pragma unroll
    for (int nt = 0; nt < 3; ++nt) {
        const int cb = nt * HDIM + wid * 16;
        const float* wrow = Whh + (size_t)(cb + rlane) * HDIM;
        bb[nt] = bhh[cb + rlane];
        #pragma unroll
        for (int kc = 0; kc < 4; ++kc) {
            const float* wp = wrow + kc * 32 + kgrp * 8;
            float4 w0 = *(const float4*)wp;
            float4 w1 = *(const float4*)(wp + 4);
            float wv[8] = {w0.x, w0.y, w0.z, w0.w, w1.x, w1.y, w1.z, w1.w};
            #pragma unroll
            for (int j = 0; j < 8; ++j) {
                short hi = f2bf(wv[j]);
                Bhi[nt][kc][j] = hi;
                Blo[nt][kc][j] = f2bf(wv[j] - bf2f(hi));
            }
        }
    }

    // ---- tile metadata ----
    if (tid < 16) {
        int pos = base + tid;
        int seq = (pos < numSeq) ? order[pos] : -1;
        sh_ord[tid] = seq;
        sh_len[tid] = (seq >= 0) ? lengths[seq] : 0;
    }
    __syncthreads();
    if (WORD) {
        for (int f = tid; f < 16 * WW; f += 512) {
            int s = f >> 6;
            int seq = sh_ord[s];
            sh_tok[f] = (seq >= 0) ? tokens[(size_t)seq * WW + (f & 63)] : 0;
        }
    }
    for (int u = tid; u < 2 * 16 * 136; u += 512) {
        ((short*)sh_hi)[u] = 0;
        ((short*)sh_lo)[u] = 0;
    }
    if (tid == 0) {
        int m = 0;
        for (int s = 0; s < 16; ++s) m = max(m, sh_len[s]);
        sh_maxlen = m;
    }
    int lens[4], ords[4];
    #pragma unroll
    for (int j = 0; j < 4; ++j) {
        lens[j] = sh_len[4 * kgrp + j];
        ords[j] = sh_ord[4 * kgrp + j];
    }
    __syncthreads();
    const int maxlen = sh_maxlen;

    auto fetch_xg = [&](int t, float* fr, float* fz, float* fn) {
        #pragma unroll
        for (int j = 0; j < 4; ++j) {
            fr[j] = 0.f; fz[j] = 0.f; fn[j] = 0.f;
            if (t < lens[j]) {
                int tt = dir ? (lens[j] - 1 - t) : t;
                size_t row;
                if (WORD) row = (size_t)sh_tok[(4 * kgrp + j) * WW + tt];
                else      row = (size_t)ords[j] * TMAX + tt;
                const float* xg = table + row * NPROJ + dir * G3 + e;
                fr[j] = xg[0]; fz[j] = xg[HDIM]; fn[j] = xg[2 * HDIM];
            }
        }
    };

    float hold[4] = {0.f, 0.f, 0.f, 0.f};
    float pAr[4], pAz[4], pAn[4];   // xg for even steps
    float pBr[4], pBz[4], pBn[4];   // xg for odd steps
    fetch_xg(0, pAr, pAz, pAn);
    fetch_xg(1, pBr, pBz, pBn);

// One GRU step. Consumes (PR,PZ,PN) at the gate, then re-fetches xg(T+2)
// into the SAME arrays (dead until two steps later -> loop-carried load).
#define GRU_STEP(T, PR, PZ, PN)                                               \
    {                                                                         \
        const int cur = (T) & 1, nxt = cur ^ 1;                               \
        bf16x8 ah[4], al[4];                                                  \
        _Pragma("unroll")                                                     \
        for (int kc = 0; kc < 4; ++kc) {                                      \
            ah[kc] = *(const bf16x8*)&sh_hi[cur][rlane][kc * 32 + kgrp * 8];  \
            al[kc] = *(const bf16x8*)&sh_lo[cur][rlane][kc * 32 + kgrp * 8];  \
        }                                                                     \
        f32x4 acc[3];                                                         \
        _Pragma("unroll")                                                     \
        for (int nt = 0; nt < 3; ++nt) {                                      \
            acc[nt] = {0.f, 0.f, 0.f, 0.f};                                   \
            _Pragma("unroll")                                                 \
            for (int kc = 0; kc < 4; ++kc)                                    \
                acc[nt] = __builtin_amdgcn_mfma_f32_16x16x32_bf16(            \
                    ah[kc], Bhi[nt][kc], acc[nt], 0, 0, 0);                   \
            _Pragma("unroll")                                                 \
            for (int kc = 0; kc < 4; ++kc)                                    \
                acc[nt] = __builtin_amdgcn_mfma_f32_16x16x32_bf16(            \
                    ah[kc], Blo[nt][kc], acc[nt], 0, 0, 0);                   \
            _Pragma("unroll")                                                 \
            for (int kc = 0; kc < 4; ++kc)                                    \
                acc[nt] = __builtin_amdgcn_mfma_f32_16x16x32_bf16(            \
                    al[kc], Bhi[nt][kc], acc[nt], 0, 0, 0);                   \
        }                                                                     \
        _Pragma("unroll")                                                     \
        for (int j = 0; j < 4; ++j) {                                         \
            if ((T) < lens[j]) {                                              \
                float hgr = acc[0][j] + bb[0];                                \
                float hgz = acc[1][j] + bb[1];                                \
                float hgn = acc[2][j] + bb[2];                                \
                float rg = fsigmoid(PR[j] + hgr);                             \
                float zg = fsigmoid(PZ[j] + hgz);                             \
                float ng = ftanh(PN[j] + rg * hgn);                           \
                hold[j] = (1.f - zg) * ng + zg * hold[j];                     \
            }                                                                 \
        }                                                                     \
        fetch_xg((T) + 2, PR, PZ, PN);                                        \
        _Pragma("unroll")                                                     \
        for (int j = 0; j < 4; ++j) {                                         \
            const int s = 4 * kgrp + j;                                       \
            short hi = f2bf(hold[j]);                                         \
            sh_hi[nxt][s][e] = hi;                                            \
            sh_lo[nxt][s][e] = f2bf(hold[j] - bf2f(hi));                      \
        }                                                                     \
        __syncthreads();                                                      \
    }

    int t = 0;
    for (; t + 1 < maxlen; t += 2) {
        GRU_STEP(t,     pAr, pAz, pAn);
        GRU_STEP(t + 1, pBr, pBz, pBn);
    }
    if (t < maxlen) {
        GRU_STEP(t, pAr, pAz, pAn);
    }
#undef GRU_STEP

    // ---- write out last-h from registers ----
    float* hout = dir ? hout_b : hout_f;
    #pragma unroll
    for (int j = 0; j < 4; ++j) {
        if (ords[j] >= 0)
            hout[(size_t)ords[j] * HDIM + e] = hold[j];
    }
}

// ---------------------------------------------------------------------------
// Head + mean
// ---------------------------------------------------------------------------
__global__ __launch_bounds__(64) void head_kernel(
    const float* __restrict__ hsf, const float* __restrict__ hsb,
    const float* __restrict__ fc1_w, const float* __restrict__ fc1_b,
    const float* __restrict__ fc2_w, const float* __restrict__ fc2_b,
    float* __restrict__ out)
{
    const int br = blockIdx.x;
    const int j = threadIdx.x;
    __shared__ float rev[HDIM];
    for (int ee = j; ee < HDIM; ee += 64)
        rev[ee] = 0.5f * (hsf[(size_t)br * HDIM + ee] + hsb[(size_t)br * HDIM + ee]);
    __syncthreads();
    float acc = 0.f;
    #pragma unroll
    for (int k = 0; k < HDIM; ++k)
        acc = fmaf(fc1_w[(size_t)j * HDIM + k], rev[k], acc);
    acc += fc1_b[j];
    const float alpha = 1.6732632423543772f;
    const float scale = 1.0507009873554805f;
    float h1 = scale * (acc > 0.f ? acc : alpha * (expf(acc) - 1.f));
    float contrib = h1 * fc2_w[j];
    #pragma unroll
    for (int off = 32; off > 0; off >>= 1)
        contrib += __shfl_down(contrib, off);
    if (j == 0) out[16 + br] = contrib + fc2_b[0];
}

__global__ void mean_kernel(float* __restrict__ out)
{
    int b = threadIdx.x;
    if (b < BB) {
        float s = 0.f;
        for (int r = 0; r < RR; ++r) s += out[16 + b * RR + r];
        out[b] = s / (float)RR;
    }
}

// ---------------------------------------------------------------------------
// Launch
// ---------------------------------------------------------------------------
extern "C" void kernel_launch(void* const* d_in, const int* in_sizes, int n_in,
                              void* d_out, int out_size, void* d_ws, size_t ws_size,
                              hipStream_t stream)
{
    const int*   inputs       = (const int*)d_in[0];
    const int*   sent_lengths = (const int*)d_in[1];
    const int*   sent_counts  = (const int*)d_in[2];
    const float* embed   = (const float*)d_in[3];
    const float* wWih_f  = (const float*)d_in[4];
    const float* wWhh_f  = (const float*)d_in[5];
    const float* wbih_f  = (const float*)d_in[6];
    const float* wbhh_f  = (const float*)d_in[7];
    const float* wWih_b  = (const float*)d_in[8];
    const float* wWhh_b  = (const float*)d_in[9];
    const float* wbih_b  = (const float*)d_in[10];
    const float* wbhh_b  = (const float*)d_in[11];
    const float* sWih_f  = (const float*)d_in[12];
    const float* sWhh_f  = (const float*)d_in[13];
    const float* sbih_f  = (const float*)d_in[14];
    const float* sbhh_f  = (const float*)d_in[15];
    const float* sWih_b  = (const float*)d_in[16];
    const float* sWhh_b  = (const float*)d_in[17];
    const float* sbih_b  = (const float*)d_in[18];
    const float* sbhh_b  = (const float*)d_in[19];
    const float* fc1_w   = (const float*)d_in[20];
    const float* fc1_b   = (const float*)d_in[21];
    const float* fc2_w   = (const float*)d_in[22];
    const float* fc2_b   = (const float*)d_in[23];

    float* ws = (float*)d_ws;
    const size_t projT_elems = (size_t)VOCAB * NPROJ;
    const size_t xgs_elems   = (size_t)NSENT * NPROJ;
    const size_t h_elems     = (size_t)NSENT * HDIM;
    const size_t hs_elems    = (size_t)NREV * HDIM;
    float* projT = ws;
    float* xgs   = projT + projT_elems;
    float* hf    = xgs + xgs_elems;
    float* hb    = hf + h_elems;
    float* hsf   = hb + h_elems;
    float* hsb   = hsf + hs_elems;
    int* order1 = (int*)(hsb + hs_elems);          // [NSENT]
    int* order2 = order1 + NSENT;                  // [NREV]

    size_t need = (projT_elems + xgs_elems + 2*h_elems + 2*hs_elems) * sizeof(float)
                + (NSENT + NREV) * sizeof(int);
    if (ws_size < need) return;

    // 0) counting sort of both length arrays (single block)
    sort_all<<<1, 256, 0, stream>>>(sent_lengths, order1, sent_counts, order2);

    // 1) projected-embedding table via split-bf16 MFMA (K=200 pad 224)
    {
        dim3 grid(NPROJ / 128, (VOCAB + 127) / 128);    // 6 x 391
        gemm_mfma_bias<EDIM, 224, false><<<grid, 256, 0, stream>>>(
            embed, nullptr, VOCAB,
            wWih_f, wWih_b, wbih_f, wbih_b, projT);
    }
    // 2) word-level BiGRU last-h (fused-gate MFMA scan)
    {
        int numTiles = NSENT / 16;                      // 200
        gru_mfma<true, WW><<<2 * numTiles, 512, 0, stream>>>(
            projT, inputs, sent_lengths, order1,
            wWhh_f, wWhh_b, wbhh_f, wbhh_b,
            hf, hb, NSENT, numTiles);
    }
    // 3) sentence-level input projections via split-bf16 MFMA (K=128, avg)
    {
        dim3 grid(NPROJ / 128, (NSENT + 127) / 128);    // 6 x 25
        gemm_mfma_bias<HDIM, HDIM, true><<<grid, 256, 0, stream>>>(
            hf, hb, NSENT,
            sWih_f, sWih_b, sbih_f, sbih_b, xgs);
    }
    // 4) sentence-level BiGRU last-h (fused-gate MFMA scan)
    {
        int numTiles = NREV / 16;                       // 10
        gru_mfma<false, SS><<<2 * numTiles, 512, 0, stream>>>(
            xgs, nullptr, sent_counts, order2,
            sWhh_f, sWhh_b, sbhh_f, sbhh_b,
            hsf, hsb, NREV, numTiles);
    }
    // 5) FC head -> r_stars, then p_stars
    head_kernel<<<NREV, 64, 0, stream>>>(hsf, hsb, fc1_w, fc1_b, fc2_w, fc2_b,
                                         (float*)d_out);
    mean_kernel<<<1, 64, 0, stream>>>((float*)d_out);
}

// Round 10
// 275.163 us; speedup vs baseline: 5.3688x; 1.1498x over previous
//
#include <hip/hip_runtime.h>
#include <hip/hip_bf16.h>
#include <cstddef>

// ---------------------------------------------------------------------------
// Problem dims
// ---------------------------------------------------------------------------
#define VOCAB 50000
#define EDIM  200
#define HDIM  128
#define BB 16
#define RR 10
#define SS 20
#define WW 64
#define NSENT (BB*RR*SS)   // 3200 word-level sequences
#define NREV  (BB*RR)      // 160 sentence-level sequences
#define G3    (3*HDIM)     // 384 gate rows per direction
#define NPROJ (2*G3)       // 768

// ---------------------------------------------------------------------------
// bf16 + fast-math helpers
// ---------------------------------------------------------------------------
static __device__ __forceinline__ short f2bf(float f) {    // RNE (for lo parts)
    union { float f; unsigned u; } v; v.f = f;
    unsigned r = v.u + 0x7FFFu + ((v.u >> 16) & 1u);
    return (short)(r >> 16);
}
static __device__ __forceinline__ short f2bf_t(float f) {  // truncate (hi parts)
    union { float f; unsigned u; } v; v.f = f;
    return (short)(v.u >> 16);
}
static __device__ __forceinline__ float bf2f(short s) {
    union { unsigned u; float f; } v;
    v.u = ((unsigned)(unsigned short)s) << 16;
    return v.f;
}
static __device__ __forceinline__ float frcp(float x) {    // v_rcp_f32, ~1 ulp
    return __builtin_amdgcn_rcpf(x);
}
static __device__ __forceinline__ float fsigmoid(float x) {
    return frcp(1.f + __expf(-x));     // mul+exp+add+rcp; rcp(inf)=0 -> safe
}
static __device__ __forceinline__ float ftanh(float x) {
    float y = __expf(-2.f * fabsf(x)); // y in (0,1], no overflow path
    float t = (1.f - y) * frcp(1.f + y);
    return copysignf(t, x);
}

// ---------------------------------------------------------------------------
// Split-bf16 MFMA GEMM, templated on K:
//   C[M x 768] = A[M x KREAL] @ [B0;B1]^T + [bias0;bias1]
// ---------------------------------------------------------------------------
#define GM_LDK 40   // shorts per LDS row: 32 + 8 pad

template<int KREAL, int KPAD, bool AVG>
__global__ __launch_bounds__(256, 2) void gemm_mfma_bias(
    const float* __restrict__ A0, const float* __restrict__ A1, int M,
    const float* __restrict__ B0, const float* __restrict__ B1,
    const float* __restrict__ bias0, const float* __restrict__ bias1,
    float* __restrict__ C)
{
    using bf16x8 = __attribute__((ext_vector_type(8))) short;
    using f32x4  = __attribute__((ext_vector_type(4))) float;

    const int ct = blockIdx.x;
    const int rt = blockIdx.y;
    const int tid = threadIdx.x;
    const int lane = tid & 63;
    const int wid  = tid >> 6;
    const int rlane = lane & 15;
    const int kgrp  = lane >> 4;

    const int rowBase = rt * 128;
    const int colBase = ct * 128;
    const float* Bsrc = (colBase < G3) ? B0 : B1;
    const int bcol = (colBase < G3) ? colBase : (colBase - G3);

    __shared__ short Ahi[128][GM_LDK], Alo[128][GM_LDK];
    __shared__ short Bhi[128][GM_LDK], Blo[128][GM_LDK];

    const int wrow = (wid >> 1) * 64;
    const int wcol = (wid & 1) * 64;

    f32x4 acc[4][4];
    #pragma unroll
    for (int i = 0; i < 4; ++i)
        #pragma unroll
        for (int j = 0; j < 4; ++j) acc[i][j] = {0.f, 0.f, 0.f, 0.f};

    const int srow = tid >> 1;
    const int skh  = (tid & 1) << 4;

    for (int k0 = 0; k0 < KPAD; k0 += 32) {
        {
            const int grow = rowBase + srow;
            float v[16];
            #pragma unroll
            for (int i = 0; i < 4; ++i) {
                const int k = k0 + skh + i * 4;
                float4 x = {0.f, 0.f, 0.f, 0.f};
                if (grow < M && k + 3 < KREAL) {
                    x = *(const float4*)&A0[(size_t)grow * KREAL + k];
                    if (AVG) {
                        float4 y = *(const float4*)&A1[(size_t)grow * KREAL + k];
                        x.x = 0.5f * (x.x + y.x); x.y = 0.5f * (x.y + y.y);
                        x.z = 0.5f * (x.z + y.z); x.w = 0.5f * (x.w + y.w);
                    }
                }
                v[4*i+0] = x.x; v[4*i+1] = x.y; v[4*i+2] = x.z; v[4*i+3] = x.w;
            }
            bf16x8 h0, h1, l0, l1;
            #pragma unroll
            for (int i = 0; i < 8; ++i) {
                short a = f2bf_t(v[i]);
                h0[i] = a; l0[i] = f2bf(v[i] - bf2f(a));
                short b = f2bf_t(v[i + 8]);
                h1[i] = b; l1[i] = f2bf(v[i + 8] - bf2f(b));
            }
            *(bf16x8*)&Ahi[srow][skh]     = h0;
            *(bf16x8*)&Ahi[srow][skh + 8] = h1;
            *(bf16x8*)&Alo[srow][skh]     = l0;
            *(bf16x8*)&Alo[srow][skh + 8] = l1;
        }
        {
            const int gcol = bcol + srow;
            float v[16];
            #pragma unroll
            for (int i = 0; i < 4; ++i) {
                const int k = k0 + skh + i * 4;
                float4 x = {0.f, 0.f, 0.f, 0.f};
                if (k + 3 < KREAL)
                    x = *(const float4*)&Bsrc[(size_t)gcol * KREAL + k];
                v[4*i+0] = x.x; v[4*i+1] = x.y; v[4*i+2] = x.z; v[4*i+3] = x.w;
            }
            bf16x8 h0, h1, l0, l1;
            #pragma unroll
            for (int i = 0; i < 8; ++i) {
                short a = f2bf_t(v[i]);
                h0[i] = a; l0[i] = f2bf(v[i] - bf2f(a));
                short b = f2bf_t(v[i + 8]);
                h1[i] = b; l1[i] = f2bf(v[i + 8] - bf2f(b));
            }
            *(bf16x8*)&Bhi[srow][skh]     = h0;
            *(bf16x8*)&Bhi[srow][skh + 8] = h1;
            *(bf16x8*)&Blo[srow][skh]     = l0;
            *(bf16x8*)&Blo[srow][skh + 8] = l1;
        }
        __syncthreads();
        bf16x8 ah[4], al[4], bh[4], bl[4];
        #pragma unroll
        for (int mr = 0; mr < 4; ++mr) {
            ah[mr] = *(const bf16x8*)&Ahi[wrow + mr * 16 + rlane][kgrp * 8];
            al[mr] = *(const bf16x8*)&Alo[wrow + mr * 16 + rlane][kgrp * 8];
        }
        #pragma unroll
        for (int nc = 0; nc < 4; ++nc) {
            bh[nc] = *(const bf16x8*)&Bhi[wcol + nc * 16 + rlane][kgrp * 8];
            bl[nc] = *(const bf16x8*)&Blo[wcol + nc * 16 + rlane][kgrp * 8];
        }
        #pragma unroll
        for (int mr = 0; mr < 4; ++mr)
            #pragma unroll
            for (int nc = 0; nc < 4; ++nc) {
                acc[mr][nc] = __builtin_amdgcn_mfma_f32_16x16x32_bf16(
                    ah[mr], bh[nc], acc[mr][nc], 0, 0, 0);
                acc[mr][nc] = __builtin_amdgcn_mfma_f32_16x16x32_bf16(
                    ah[mr], bl[nc], acc[mr][nc], 0, 0, 0);
                acc[mr][nc] = __builtin_amdgcn_mfma_f32_16x16x32_bf16(
                    al[mr], bh[nc], acc[mr][nc], 0, 0, 0);
            }
        __syncthreads();
    }

    const float* bs = (colBase < G3) ? bias0 : bias1;
    #pragma unroll
    for (int nc = 0; nc < 4; ++nc) {
        const int c = wcol + nc * 16 + rlane;
        const float bv = bs[bcol + c];
        #pragma unroll
        for (int mr = 0; mr < 4; ++mr) {
            #pragma unroll
            for (int r = 0; r < 4; ++r) {
                const int grow = rowBase + wrow + mr * 16 + kgrp * 4 + r;
                if (grow < M)
                    C[(size_t)grow * NPROJ + colBase + c] = acc[mr][nc][r] + bv;
            }
        }
    }
}

// ---------------------------------------------------------------------------
// Single-block counting sort for BOTH length arrays.
// ---------------------------------------------------------------------------
__global__ __launch_bounds__(256) void sort_all(
    const int* __restrict__ len1, int* __restrict__ order1,
    const int* __restrict__ len2, int* __restrict__ order2)
{
    __shared__ int hist[65];
    const int tid = threadIdx.x;

    for (int i = tid; i < 65; i += 256) hist[i] = 0;
    __syncthreads();
    for (int i = tid; i < NSENT; i += 256) atomicAdd(&hist[len1[i]], 1);
    __syncthreads();
    if (tid == 0) {
        int acc = 0;
        for (int l = 1; l <= WW; ++l) { int c = hist[l]; hist[l] = acc; acc += c; }
    }
    __syncthreads();
    for (int i = tid; i < NSENT; i += 256) {
        int pos = atomicAdd(&hist[len1[i]], 1);
        order1[pos] = i;
    }
    __syncthreads();
    for (int i = tid; i < 65; i += 256) hist[i] = 0;
    __syncthreads();
    for (int i = tid; i < NREV; i += 256) atomicAdd(&hist[len2[i]], 1);
    __syncthreads();
    if (tid == 0) {
        int acc = 0;
        for (int l = 1; l <= SS; ++l) { int c = hist[l]; hist[l] = acc; acc += c; }
    }
    __syncthreads();
    for (int i = tid; i < NREV; i += 256) {
        int pos = atomicAdd(&hist[len2[i]], 1);
        order2[pos] = i;
    }
}

// ---------------------------------------------------------------------------
// MFMA GRU scan, fused-gate, depth-2 xg prefetch (2-body unroll), rcp gates.
// ---------------------------------------------------------------------------
template<bool WORD, int TMAX>
__global__ __launch_bounds__(512, 2) void gru_mfma(
    const float* __restrict__ table,
    const int*   __restrict__ tokens,
    const int*   __restrict__ lengths,
    const int*   __restrict__ order,
    const float* __restrict__ Whh_f, const float* __restrict__ Whh_b,
    const float* __restrict__ bhh_f, const float* __restrict__ bhh_b,
    float* __restrict__ hout_f, float* __restrict__ hout_b,
    int numSeq, int numTiles)
{
    using bf16x8 = __attribute__((ext_vector_type(8))) short;
    using f32x4  = __attribute__((ext_vector_type(4))) float;

    const int dir  = (blockIdx.x >= numTiles) ? 1 : 0;
    const int rawt = dir ? (blockIdx.x - numTiles) : blockIdx.x;
    const int tile = numTiles - 1 - rawt;      // longest tiles first
    const int base = tile * 16;
    const int tid  = threadIdx.x;              // 0..511
    const int lane = tid & 63;
    const int wid  = tid >> 6;                 // 0..7
    const int rlane = lane & 15;
    const int kgrp  = lane >> 4;               // 0..3
    const int e = wid * 16 + rlane;            // this lane's gate element

    __shared__ __align__(16) short sh_hi[2][16][136];
    __shared__ __align__(16) short sh_lo[2][16][136];
    __shared__ int sh_len[16];
    __shared__ int sh_ord[16];
    __shared__ int sh_tok[WORD ? 16 * WW : 1];
    __shared__ int sh_maxlen;

    // ---- per-wave weight fragments ----
    const float* Whh = dir ? Whh_b : Whh_f;
    const float* bhh = dir ? bhh_b : bhh_f;
    bf16x8 Bhi[3][4], Blo[3][4];
    float bb[3];
    #pragma unroll
    for (int nt = 0; nt < 3; ++nt) {
        const int cb = nt * HDIM + wid * 16;
        const float* wrow = Whh + (size_t)(cb + rlane) * HDIM;
        bb[nt] = bhh[cb + rlane];
        #pragma unroll
        for (int kc = 0; kc < 4; ++kc) {
            const float* wp = wrow + kc * 32 + kgrp * 8;
            float4 w0 = *(const float4*)wp;
            float4 w1 = *(const float4*)(wp + 4);
            float wv[8] = {w0.x, w0.y, w0.z, w0.w, w1.x, w1.y, w1.z, w1.w};
            #pragma unroll
            for (int j = 0; j < 8; ++j) {
                short hi = f2bf_t(wv[j]);
                Bhi[nt][kc][j] = hi;
                Blo[nt][kc][j] = f2bf(wv[j] - bf2f(hi));
            }
        }
    }

    // ---- tile metadata ----
    if (tid < 16) {
        int pos = base + tid;
        int seq = (pos < numSeq) ? order[pos] : -1;
        sh_ord[tid] = seq;
        sh_len[tid] = (seq >= 0) ? lengths[seq] : 0;
    }
    __syncthreads();
    if (WORD) {
        for (int f = tid; f < 16 * WW; f += 512) {
            int s = f >> 6;
            int seq = sh_ord[s];
            sh_tok[f] = (seq >= 0) ? tokens[(size_t)seq * WW + (f & 63)] : 0;
        }
    }
    for (int u = tid; u < 2 * 16 * 136; u += 512) {
        ((short*)sh_hi)[u] = 0;
        ((short*)sh_lo)[u] = 0;
    }
    if (tid == 0) {
        int m = 0;
        for (int s = 0; s < 16; ++s) m = max(m, sh_len[s]);
        sh_maxlen = m;
    }
    int lens[4], ords[4];
    #pragma unroll
    for (int j = 0; j < 4; ++j) {
        lens[j] = sh_len[4 * kgrp + j];
        ords[j] = sh_ord[4 * kgrp + j];
    }
    __syncthreads();
    const int maxlen = sh_maxlen;

    auto fetch_xg = [&](int t, float* fr, float* fz, float* fn) {
        #pragma unroll
        for (int j = 0; j < 4; ++j) {
            fr[j] = 0.f; fz[j] = 0.f; fn[j] = 0.f;
            if (t < lens[j]) {
                int tt = dir ? (lens[j] - 1 - t) : t;
                size_t row;
                if (WORD) row = (size_t)sh_tok[(4 * kgrp + j) * WW + tt];
                else      row = (size_t)ords[j] * TMAX + tt;
                const float* xg = table + row * NPROJ + dir * G3 + e;
                fr[j] = xg[0]; fz[j] = xg[HDIM]; fn[j] = xg[2 * HDIM];
            }
        }
    };

    float hold[4] = {0.f, 0.f, 0.f, 0.f};
    float pAr[4], pAz[4], pAn[4];   // xg for even steps
    float pBr[4], pBz[4], pBn[4];   // xg for odd steps
    fetch_xg(0, pAr, pAz, pAn);
    fetch_xg(1, pBr, pBz, pBn);

#define GRU_STEP(T, PR, PZ, PN)                                               \
    {                                                                         \
        const int cur = (T) & 1, nxt = cur ^ 1;                               \
        bf16x8 ah[4], al[4];                                                  \
        _Pragma("unroll")                                                     \
        for (int kc = 0; kc < 4; ++kc) {                                      \
            ah[kc] = *(const bf16x8*)&sh_hi[cur][rlane][kc * 32 + kgrp * 8];  \
            al[kc] = *(const bf16x8*)&sh_lo[cur][rlane][kc * 32 + kgrp * 8];  \
        }                                                                     \
        f32x4 acc[3];                                                         \
        _Pragma("unroll")                                                     \
        for (int nt = 0; nt < 3; ++nt) {                                      \
            acc[nt] = {0.f, 0.f, 0.f, 0.f};                                   \
            _Pragma("unroll")                                                 \
            for (int kc = 0; kc < 4; ++kc)                                    \
                acc[nt] = __builtin_amdgcn_mfma_f32_16x16x32_bf16(            \
                    ah[kc], Bhi[nt][kc], acc[nt], 0, 0, 0);                   \
            _Pragma("unroll")                                                 \
            for (int kc = 0; kc < 4; ++kc)                                    \
                acc[nt] = __builtin_amdgcn_mfma_f32_16x16x32_bf16(            \
                    ah[kc], Blo[nt][kc], acc[nt], 0, 0, 0);                   \
            _Pragma("unroll")                                                 \
            for (int kc = 0; kc < 4; ++kc)                                    \
                acc[nt] = __builtin_amdgcn_mfma_f32_16x16x32_bf16(            \
                    al[kc], Bhi[nt][kc], acc[nt], 0, 0, 0);                   \
        }                                                                     \
        _Pragma("unroll")                                                     \
        for (int j = 0; j < 4; ++j) {                                         \
            if ((T) < lens[j]) {                                              \
                float hgr = acc[0][j] + bb[0];                                \
                float hgz = acc[1][j] + bb[1];                                \
                float hgn = acc[2][j] + bb[2];                                \
                float rg = fsigmoid(PR[j] + hgr);                             \
                float zg = fsigmoid(PZ[j] + hgz);                             \
                float ng = ftanh(PN[j] + rg * hgn);                           \
                hold[j] = (1.f - zg) * ng + zg * hold[j];                     \
            }                                                                 \
        }                                                                     \
        fetch_xg((T) + 2, PR, PZ, PN);                                        \
        _Pragma("unroll")                                                     \
        for (int j = 0; j < 4; ++j) {                                         \
            const int s = 4 * kgrp + j;                                       \
            short hi = f2bf_t(hold[j]);                                       \
            sh_hi[nxt][s][e] = hi;                                            \
            sh_lo[nxt][s][e] = f2bf(hold[j] - bf2f(hi));                      \
        }                                                                     \
        __syncthreads();                                                      \
    }

    int t = 0;
    for (; t + 1 < maxlen; t += 2) {
        GRU_STEP(t,     pAr, pAz, pAn);
        GRU_STEP(t + 1, pBr, pBz, pBn);
    }
    if (t < maxlen) {
        GRU_STEP(t, pAr, pAz, pAn);
    }
#undef GRU_STEP

    // ---- write out last-h from registers ----
    float* hout = dir ? hout_b : hout_f;
    #pragma unroll
    for (int j = 0; j < 4; ++j) {
        if (ords[j] >= 0)
            hout[(size_t)ords[j] * HDIM + e] = hold[j];
    }
}

// ---------------------------------------------------------------------------
// Head + mean
// ---------------------------------------------------------------------------
__global__ __launch_bounds__(64) void head_kernel(
    const float* __restrict__ hsf, const float* __restrict__ hsb,
    const float* __restrict__ fc1_w, const float* __restrict__ fc1_b,
    const float* __restrict__ fc2_w, const float* __restrict__ fc2_b,
    float* __restrict__ out)
{
    const int br = blockIdx.x;
    const int j = threadIdx.x;
    __shared__ float rev[HDIM];
    for (int ee = j; ee < HDIM; ee += 64)
        rev[ee] = 0.5f * (hsf[(size_t)br * HDIM + ee] + hsb[(size_t)br * HDIM + ee]);
    __syncthreads();
    float acc = 0.f;
    #pragma unroll
    for (int k = 0; k < HDIM; ++k)
        acc = fmaf(fc1_w[(size_t)j * HDIM + k], rev[k], acc);
    acc += fc1_b[j];
    const float alpha = 1.6732632423543772f;
    const float scale = 1.0507009873554805f;
    float h1 = scale * (acc > 0.f ? acc : alpha * (expf(acc) - 1.f));
    float contrib = h1 * fc2_w[j];
    #pragma unroll
    for (int off = 32; off > 0; off >>= 1)
        contrib += __shfl_down(contrib, off);
    if (j == 0) out[16 + br] = contrib + fc2_b[0];
}

__global__ void mean_kernel(float* __restrict__ out)
{
    int b = threadIdx.x;
    if (b < BB) {
        float s = 0.f;
        for (int r = 0; r < RR; ++r) s += out[16 + b * RR + r];
        out[b] = s / (float)RR;
    }
}

// ---------------------------------------------------------------------------
// Launch
// ---------------------------------------------------------------------------
extern "C" void kernel_launch(void* const* d_in, const int* in_sizes, int n_in,
                              void* d_out, int out_size, void* d_ws, size_t ws_size,
                              hipStream_t stream)
{
    const int*   inputs       = (const int*)d_in[0];
    const int*   sent_lengths = (const int*)d_in[1];
    const int*   sent_counts  = (const int*)d_in[2];
    const float* embed   = (const float*)d_in[3];
    const float* wWih_f  = (const float*)d_in[4];
    const float* wWhh_f  = (const float*)d_in[5];
    const float* wbih_f  = (const float*)d_in[6];
    const float* wbhh_f  = (const float*)d_in[7];
    const float* wWih_b  = (const float*)d_in[8];
    const float* wWhh_b  = (const float*)d_in[9];
    const float* wbih_b  = (const float*)d_in[10];
    const float* wbhh_b  = (const float*)d_in[11];
    const float* sWih_f  = (const float*)d_in[12];
    const float* sWhh_f  = (const float*)d_in[13];
    const float* sbih_f  = (const float*)d_in[14];
    const float* sbhh_f  = (const float*)d_in[15];
    const float* sWih_b  = (const float*)d_in[16];
    const float* sWhh_b  = (const float*)d_in[17];
    const float* sbih_b  = (const float*)d_in[18];
    const float* sbhh_b  = (const float*)d_in[19];
    const float* fc1_w   = (const float*)d_in[20];
    const float* fc1_b   = (const float*)d_in[21];
    const float* fc2_w   = (const float*)d_in[22];
    const float* fc2_b   = (const float*)d_in[23];

    float* ws = (float*)d_ws;
    const size_t projT_elems = (size_t)VOCAB * NPROJ;
    const size_t xgs_elems   = (size_t)NSENT * NPROJ;
    const size_t h_elems     = (size_t)NSENT * HDIM;
    const size_t hs_elems    = (size_t)NREV * HDIM;
    float* projT = ws;
    float* xgs   = projT + projT_elems;
    float* hf    = xgs + xgs_elems;
    float* hb    = hf + h_elems;
    float* hsf   = hb + h_elems;
    float* hsb   = hsf + hs_elems;
    int* order1 = (int*)(hsb + hs_elems);          // [NSENT]
    int* order2 = order1 + NSENT;                  // [NREV]

    size_t need = (projT_elems + xgs_elems + 2*h_elems + 2*hs_elems) * sizeof(float)
                + (NSENT + NREV) * sizeof(int);
    if (ws_size < need) return;

    // 0) counting sort of both length arrays (single block)
    sort_all<<<1, 256, 0, stream>>>(sent_lengths, order1, sent_counts, order2);

    // 1) projected-embedding table via split-bf16 MFMA (K=200 pad 224)
    {
        dim3 grid(NPROJ / 128, (VOCAB + 127) / 128);    // 6 x 391
        gemm_mfma_bias<EDIM, 224, false><<<grid, 256, 0, stream>>>(
            embed, nullptr, VOCAB,
            wWih_f, wWih_b, wbih_f, wbih_b, projT);
    }
    // 2) word-level BiGRU last-h (fused-gate MFMA scan)
    {
        int numTiles = NSENT / 16;                      // 200
        gru_mfma<true, WW><<<2 * numTiles, 512, 0, stream>>>(
            projT, inputs, sent_lengths, order1,
            wWhh_f, wWhh_b, wbhh_f, wbhh_b,
            hf, hb, NSENT, numTiles);
    }
    // 3) sentence-level input projections via split-bf16 MFMA (K=128, avg)
    {
        dim3 grid(NPROJ / 128, (NSENT + 127) / 128);    // 6 x 25
        gemm_mfma_bias<HDIM, HDIM, true><<<grid, 256, 0, stream>>>(
            hf, hb, NSENT,
            sWih_f, sWih_b, sbih_f, sbih_b, xgs);
    }
    // 4) sentence-level BiGRU last-h (fused-gate MFMA scan)
    {
        int numTiles = NREV / 16;                       // 10
        gru_mfma<false, SS><<<2 * numTiles, 512, 0, stream>>>(
            xgs, nullptr, sent_counts, order2,
            sWhh_f, sWhh_b, sbhh_f, sbhh_b,
            hsf, hsb, NREV, numTiles);
    }
    // 5) FC head -> r_stars, then p_stars
    head_kernel<<<NREV, 64, 0, stream>>>(hsf, hsb, fc1_w, fc1_b, fc2_w, fc2_b,
                                         (float*)d_out);
    mean_kernel<<<1, 64, 0, stream>>>((float*)d_out);
}